// Round 7
// baseline (775.591 us; speedup 1.0000x reference)
//
#include <hip/hip_runtime.h>

// QuantMHSANet: Brevitas-style per-tensor fake-quant MHSA.
// S=2048 B=4 E=512 H=8 D=64. All GEMMs run as integer-exact bf16 MFMA.
constexpr int cS = 2048, cB = 4, cE = 512, cH = 8, cD = 64;
constexpr int cSB = cS * cB;   // 8192 rows
constexpr int cBH = cB * cH;   // 32 (b,h) pairs
constexpr int cN  = cSB * cE;  // 4194304 elements

typedef __bf16 v8bf  __attribute__((ext_vector_type(8)));
typedef float  f32x4 __attribute__((ext_vector_type(4)));

constexpr float cLOG2E = 1.4426950408889634f;

// ---- stat slots (float) ----
// 0 amax_x | 1..4 amax_w(q,k,v,o) | 5 amax_q 6 amax_k 7 amax_v | 8 max_invz
// 9 amax_ctx | 10 amax_y | 11 s0 | 12 s_in | 13..16 s_w(q,k,v,o) |
// 17 s_q 18 s_k 19 s_v | 20 scale_a 21 inv_scale_a 22 ctx_scale | 23 s_c | 24 s_y |
// 25 s_q*s_k | 26 s_q*s_k*log2e

// Quantized ints |v|<=255 have <=8 significand bits -> bf16 truncation is exact.
__device__ __forceinline__ unsigned short q2bf(float f) {
  return (unsigned short)(__float_as_uint(f) >> 16);
}
__device__ __forceinline__ float clip8(float t) { return fminf(fmaxf(t, -128.f), 127.f); }
__device__ __forceinline__ float wave_max(float v) {
#pragma unroll
  for (int o = 32; o > 0; o >>= 1) v = fmaxf(v, __shfl_down(v, o));
  return v;
}

// ---------------- reductions & scales ----------------
__global__ void absmax_kernel(const float* __restrict__ p, int n4, unsigned* slot) {
  int tid = blockIdx.x * blockDim.x + threadIdx.x, stride = gridDim.x * blockDim.x;
  float m = 0.f;
  for (int i = tid; i < n4; i += stride) {
    float4 v = ((const float4*)p)[i];
    m = fmaxf(m, fmaxf(fmaxf(fabsf(v.x), fabsf(v.y)), fmaxf(fabsf(v.z), fabsf(v.w))));
  }
  m = wave_max(m);
  __shared__ float sm[4];
  int lane = threadIdx.x & 63, wid = threadIdx.x >> 6;
  if (lane == 0) sm[wid] = m;
  __syncthreads();
  if (threadIdx.x == 0) {
    float mm = sm[0];
    for (int w = 1; w < (int)blockDim.x / 64; ++w) mm = fmaxf(mm, sm[w]);
    atomicMax(slot, __float_as_uint(mm));
  }
}

// 4 weight matrices in one launch (blockIdx.y selects)
__global__ void absmax4_kernel(const float* __restrict__ w0, const float* __restrict__ w1,
                               const float* __restrict__ w2, const float* __restrict__ w3,
                               int n4, unsigned* slots) {
  int y = blockIdx.y;
  const float* p = (y == 0) ? w0 : (y == 1) ? w1 : (y == 2) ? w2 : w3;
  int tid = blockIdx.x * blockDim.x + threadIdx.x, stride = gridDim.x * blockDim.x;
  float m = 0.f;
  for (int i = tid; i < n4; i += stride) {
    float4 v = ((const float4*)p)[i];
    m = fmaxf(m, fmaxf(fmaxf(fabsf(v.x), fabsf(v.y)), fmaxf(fabsf(v.z), fabsf(v.w))));
  }
  m = wave_max(m);
  __shared__ float sm[4];
  int lane = threadIdx.x & 63, wid = threadIdx.x >> 6;
  if (lane == 0) sm[wid] = m;
  __syncthreads();
  if (threadIdx.x == 0) {
    float mm = fmaxf(fmaxf(sm[0], sm[1]), fmaxf(sm[2], sm[3]));
    atomicMax(slots + y, __float_as_uint(mm));
  }
}

__global__ void scales_kernel(float* st, int stage) {
  if (stage == 0) {
    float s0 = fmaxf(st[0], 1e-8f) / 127.f;
    st[11] = s0;
    float mxq = s0 * 127.f;                 // max|xq| (max int is always 127)
    st[12] = fmaxf(mxq, 1e-8f) / 127.f;     // s_in
    for (int i = 0; i < 4; ++i) st[13 + i] = fmaxf(st[1 + i], 1e-8f) / 127.f;
  } else if (stage == 1) {
    st[17] = fmaxf(st[5] * 0.125f, 1e-8f) / 127.f;  // s_q (q/sqrt(64))
    st[18] = fmaxf(st[6], 1e-8f) / 127.f;           // s_k
    st[19] = fmaxf(st[7], 1e-8f) / 127.f;           // s_v
    st[25] = st[17] * st[18];
    st[26] = st[25] * cLOG2E;
  } else if (stage == 2) {
    float sa = fmaxf(st[8], 1e-8f) / 255.f;         // max(attn)=1/minZ
    st[20] = sa; st[21] = 1.f / sa; st[22] = sa * st[19];
  } else if (stage == 3) {
    st[23] = fmaxf(st[9], 1e-8f) / 127.f;           // s_c
  } else {
    st[24] = fmaxf(st[10], 1e-8f) / 127.f;          // s_y
  }
}

// ---------------- elementwise quantizers ----------------
__global__ void quant_x_kernel(const float* __restrict__ x, unsigned short* __restrict__ xq,
                               const float* st, int n4) {
  float s0 = st[11], si = st[12];
  int tid = blockIdx.x * blockDim.x + threadIdx.x, stride = gridDim.x * blockDim.x;
  for (int i = tid; i < n4; i += stride) {
    float4 v = ((const float4*)x)[i];
    ushort4 o; float t;
    t = s0 * clip8(rintf(v.x / s0)); o.x = q2bf(clip8(rintf(t / si)));
    t = s0 * clip8(rintf(v.y / s0)); o.y = q2bf(clip8(rintf(t / si)));
    t = s0 * clip8(rintf(v.z / s0)); o.z = q2bf(clip8(rintf(t / si)));
    t = s0 * clip8(rintf(v.w / s0)); o.w = q2bf(clip8(rintf(t / si)));
    ((ushort4*)xq)[i] = o;
  }
}

// 4 weight matrices quantized in one launch; outputs contiguous at outbase + y*cE*cE
__global__ void quant_w4_kernel(const float* __restrict__ w0, const float* __restrict__ w1,
                                const float* __restrict__ w2, const float* __restrict__ w3,
                                unsigned short* __restrict__ outbase, int n4, const float* st) {
  int y = blockIdx.y;
  const float* in = (y == 0) ? w0 : (y == 1) ? w1 : (y == 2) ? w2 : w3;
  unsigned short* outp = outbase + (size_t)y * cE * cE;
  float s = st[13 + y];
  int tid = blockIdx.x * blockDim.x + threadIdx.x, stride = gridDim.x * blockDim.x;
  for (int i = tid; i < n4; i += stride) {
    float4 v = ((const float4*)in)[i];
    ushort4 o;
    o.x = q2bf(clip8(rintf(v.x / s)));
    o.y = q2bf(clip8(rintf(v.y / s)));
    o.z = q2bf(clip8(rintf(v.z / s)));
    o.w = q2bf(clip8(rintf(v.w / s)));
    ((ushort4*)outp)[i] = o;
  }
}

__global__ void quant_s8_kernel(const float* __restrict__ in, unsigned short* __restrict__ outp,
                                int n4, const float* st, int slot, float premul) {
  float s = st[slot];
  int tid = blockIdx.x * blockDim.x + threadIdx.x, stride = gridDim.x * blockDim.x;
  for (int i = tid; i < n4; i += stride) {
    float4 v = ((const float4*)in)[i];
    ushort4 o;
    o.x = q2bf(clip8(rintf(v.x * premul / s)));
    o.y = q2bf(clip8(rintf(v.y * premul / s)));
    o.z = q2bf(clip8(rintf(v.z * premul / s)));
    o.w = q2bf(clip8(rintf(v.w * premul / s)));
    ((ushort4*)outp)[i] = o;
  }
}

// q and k quantized in one launch (blockIdx.y: 0=q premul 1/8 slot17, 1=k slot18)
__global__ void quant_qk_kernel(const float* __restrict__ qf, unsigned short* __restrict__ qsb,
                                int n4, const float* st) {
  int y = blockIdx.y;
  const float* in = qf + (size_t)y * cN;
  unsigned short* outp = qsb + (size_t)y * cN;
  float s = st[17 + y];
  float premul = y ? 1.0f : 0.125f;
  int tid = blockIdx.x * blockDim.x + threadIdx.x, stride = gridDim.x * blockDim.x;
  for (int i = tid; i < n4; i += stride) {
    float4 v = ((const float4*)in)[i];
    ushort4 o;
    o.x = q2bf(clip8(rintf(v.x * premul / s)));
    o.y = q2bf(clip8(rintf(v.y * premul / s)));
    o.z = q2bf(clip8(rintf(v.z * premul / s)));
    o.w = q2bf(clip8(rintf(v.w * premul / s)));
    ((ushort4*)outp)[i] = o;
  }
}

// q/k/v biases in one launch; outputs contiguous at bdst + y*512
__global__ void bias3_kernel(const float* __restrict__ b0, const float* __restrict__ b1,
                             const float* __restrict__ b2, float* __restrict__ bdst,
                             const float* st) {
  int y = blockIdx.y;
  const float* bsrc = (y == 0) ? b0 : (y == 1) ? b1 : b2;
  int f = blockIdx.x * blockDim.x + threadIdx.x;
  if (f < cE) {
    float s = st[12] * st[13 + y];
    bdst[y * cE + f] = s * rintf(bsrc[f] / s);
  }
}

__global__ void bias_kernel(const float* __restrict__ bsrc, float* __restrict__ bdst,
                            const float* st, int slot_in, int slot_w) {
  int f = blockIdx.x * blockDim.x + threadIdx.x;
  if (f < cE) {
    float s = st[slot_in] * st[slot_w];
    bdst[f] = s * rintf(bsrc[f] / s);   // int32 clip is a no-op at these magnitudes
  }
}

// V: [BH][S][D] f32 -> quantized, transposed [BH][D][S] bf16 (K-major for PV B-frags)
__global__ __launch_bounds__(256) void quant_vT_kernel(const float* __restrict__ v,
                                                       unsigned short* __restrict__ vT,
                                                       const float* st) {
  __shared__ unsigned short tile[64][65];
  int bh = blockIdx.y, s0 = blockIdx.x * 64;
  float sv = st[19];
  int td = threadIdx.x & 63, tr = threadIdx.x >> 6;
  for (int r = tr; r < 64; r += 4)
    tile[r][td] = q2bf(clip8(rintf(v[((size_t)bh * cS + s0 + r) * cD + td] / sv)));
  __syncthreads();
  for (int r = tr; r < 64; r += 4)
    vT[((size_t)bh * cD + r) * cS + s0 + td] = tile[td][r];
}

__global__ void final_quant_kernel(float* __restrict__ y, const float* st, int n4) {
  float s = st[24];
  int tid = blockIdx.x * blockDim.x + threadIdx.x, stride = gridDim.x * blockDim.x;
  for (int i = tid; i < n4; i += stride) {
    float4 v = ((float4*)y)[i];
    v.x = s * clip8(rintf(v.x / s)); v.y = s * clip8(rintf(v.y / s));
    v.z = s * clip8(rintf(v.z / s)); v.w = s * clip8(rintf(v.w / s));
    ((float4*)y)[i] = v;
  }
}

// ---------------- integer-exact bf16 MFMA GEMM ----------------
// C[row,col] = sum_e A[row][e]*W[col][e]; both stored K-major (512 cols bf16-int).
// OUTMODE 0: write [B][H][S][D] (heads split) ; OUTMODE 1: write row-major [SB][E].
template <int OUTMODE>
__global__ __launch_bounds__(256) void gemm_kernel(const unsigned short* __restrict__ A,
                                                   const unsigned short* __restrict__ Wb,
                                                   const float* __restrict__ bias,
                                                   float* __restrict__ out, const float* st,
                                                   int slot_in, int slot_w, unsigned* amax_slot) {
  int wid = threadIdx.x >> 6, lane = threadIdx.x & 63;
  int wm = wid >> 1, wn = wid & 1;
  int row0 = blockIdx.x * 64 + wm * 32;
  int col0 = blockIdx.y * 64 + wn * 32;
  int lr = lane & 15, lk = (lane >> 4) * 8;
  f32x4 acc[2][2] = {};
  const unsigned short* a0p = A + (size_t)(row0 + lr) * cE + lk;
  const unsigned short* a1p = A + (size_t)(row0 + 16 + lr) * cE + lk;
  const unsigned short* b0p = Wb + (size_t)(col0 + lr) * cE + lk;
  const unsigned short* b1p = Wb + (size_t)(col0 + 16 + lr) * cE + lk;
  for (int e0 = 0; e0 < cE; e0 += 32) {
    v8bf a0 = *(const v8bf*)(a0p + e0), a1 = *(const v8bf*)(a1p + e0);
    v8bf b0 = *(const v8bf*)(b0p + e0), b1 = *(const v8bf*)(b1p + e0);
    acc[0][0] = __builtin_amdgcn_mfma_f32_16x16x32_bf16(a0, b0, acc[0][0], 0, 0, 0);
    acc[0][1] = __builtin_amdgcn_mfma_f32_16x16x32_bf16(a0, b1, acc[0][1], 0, 0, 0);
    acc[1][0] = __builtin_amdgcn_mfma_f32_16x16x32_bf16(a1, b0, acc[1][0], 0, 0, 0);
    acc[1][1] = __builtin_amdgcn_mfma_f32_16x16x32_bf16(a1, b1, acc[1][1], 0, 0, 0);
  }
  float scale = st[slot_in] * st[slot_w];
  float lmax = 0.f;
#pragma unroll
  for (int mi = 0; mi < 2; ++mi)
#pragma unroll
    for (int ni = 0; ni < 2; ++ni)
#pragma unroll
      for (int r = 0; r < 4; ++r) {
        int row = row0 + mi * 16 + (lane >> 4) * 4 + r;   // C/D: row=(l>>4)*4+reg
        int col = col0 + ni * 16 + lr;                    //      col=l&15
        float val = scale * acc[mi][ni][r] + bias[col];
        lmax = fmaxf(lmax, fabsf(val));
        if (OUTMODE == 0) {
          int s = row >> 2, bb = row & 3, h = col >> 6, d = col & 63;
          out[(((size_t)(bb * cH + h)) * cS + s) * cD + d] = val;
        } else {
          out[(size_t)row * cE + col] = val;
        }
      }
  lmax = wave_max(lmax);
  if (lane == 0) atomicMax(amax_slot, __float_as_uint(lmax));
}

// ---------------- attention pass 1: per-row (m2, 1/Z) in log2 domain ----------------
// Swapped QK (A=K frag, B=Q frag): each lane owns q-row = lane&15, k = (lane>>4)*4+r
// per 16-block. Fully per-lane online softmax; 2-step cross-group merge at the end.
// K tiles register-prefetched one iteration ahead. launch_bounds(256,3): ~168-VGPR
// budget so K0/K1 prefetch regs actually stay resident (R4: default budget 64 ->
// compiler rematerialized loads at use, killing the pipeline; VGPR_Count was 56).
__global__ __launch_bounds__(256, 3) void attn_pass1_kernel(const unsigned short* __restrict__ qs,
                                                            const unsigned short* __restrict__ ks,
                                                            float* __restrict__ marr,
                                                            float* __restrict__ izarr,
                                                            const float* st, unsigned* maxiz_slot) {
  int bh = blockIdx.y;
  int wid = threadIdx.x >> 6, lane = threadIdx.x & 63;
  int lr = lane & 15, g = lane >> 4, lk = g * 8;
  int r0 = blockIdx.x * 64 + wid * 16;
  float sscale2 = st[26];   // s_q*s_k*log2e  (log2-domain scores)
  v8bf aq0 = *(const v8bf*)(qs + ((size_t)bh * cS + r0 + lr) * cD + lk);
  v8bf aq1 = *(const v8bf*)(qs + ((size_t)bh * cS + r0 + lr) * cD + 32 + lk);
  const unsigned short* Kbase = ks + (size_t)bh * cS * cD;

  v8bf K0[4], K1[4];
#pragma unroll
  for (int jc = 0; jc < 4; ++jc) {
    const unsigned short* p = Kbase + (size_t)(jc * 16 + lr) * cD + lk;
    K0[jc] = *(const v8bf*)p; K1[jc] = *(const v8bf*)(p + 32);
  }
  float pm = -1e30f, zs = 0.f;
  for (int kt = 0; kt < cS; kt += 64) {
    f32x4 s4[4];
#pragma unroll
    for (int jc = 0; jc < 4; ++jc) {
      f32x4 z = {0.f, 0.f, 0.f, 0.f};
      z = __builtin_amdgcn_mfma_f32_16x16x32_bf16(K0[jc], aq0, z, 0, 0, 0);
      z = __builtin_amdgcn_mfma_f32_16x16x32_bf16(K1[jc], aq1, z, 0, 0, 0);
      s4[jc] = z;
    }
    // prefetch next K tile (last iter reads past ks into vTb scratch — values unused)
#pragma unroll
    for (int jc = 0; jc < 4; ++jc) {
      const unsigned short* p = Kbase + (size_t)(kt + 64 + jc * 16 + lr) * cD + lk;
      K0[jc] = *(const v8bf*)p; K1[jc] = *(const v8bf*)(p + 32);
    }
    float t[16];
#pragma unroll
    for (int jc = 0; jc < 4; ++jc)
#pragma unroll
      for (int r = 0; r < 4; ++r) t[jc * 4 + r] = s4[jc][r] * sscale2;
    float tm = t[0];
#pragma unroll
    for (int i = 1; i < 16; ++i) tm = fmaxf(tm, t[i]);
    float nm = fmaxf(pm, tm);
    float acc = zs * __builtin_amdgcn_exp2f(pm - nm);
#pragma unroll
    for (int i = 0; i < 16; ++i) acc += __builtin_amdgcn_exp2f(t[i] - nm);
    zs = acc; pm = nm;
  }
  // merge the 4 groups (lanes lr, lr+16, lr+32, lr+48)
#pragma unroll
  for (int o = 16; o < 64; o <<= 1) {
    float mo = __shfl_xor(pm, o);
    float zo = __shfl_xor(zs, o);
    float nm = fmaxf(pm, mo);
    zs = zs * __builtin_amdgcn_exp2f(pm - nm) + zo * __builtin_amdgcn_exp2f(mo - nm);
    pm = nm;
  }
  float iz = 1.0f / zs;
  if (g == 0) {
    marr[bh * cS + r0 + lr] = pm;    // log2-domain row max
    izarr[bh * cS + r0 + lr] = iz;
  }
  float wmax = wave_max(iz);
  if (lane == 0) atomicMax(maxiz_slot, __float_as_uint(wmax));
}

// ---------------- attention pass 2: P=u8-quant(softmax) ; ctx += P*V ----------------
// Swapped QK + per-lane softmax + packed b64 P-store + 1-iter software pipeline:
// iter kt: QK[kt]+store P[kt] (buf^1) ; PV of P[kt-64] (buf) with V[kt-64] regs;
// K[kt+64] and V[kt] register-prefetched. launch_bounds(256,2): 256-VGPR budget —
// K0/K1/V0/V1 (64 regs) + aq + cacc must stay resident or the prefetch collapses
// into at-use reloads (R4 counter evidence: VGPR_Count=56, MfmaUtil 5.6%).
__global__ __launch_bounds__(256, 2) void attn_pass2_kernel(
    const unsigned short* __restrict__ qs, const unsigned short* __restrict__ ks,
    const unsigned short* __restrict__ vT, const float* __restrict__ marr,
    const float* __restrict__ izarr, float* __restrict__ ctx, const float* st,
    unsigned* amax_slot) {
  __shared__ __align__(16) unsigned short plds[4][2][16][88];  // stride 176B: b128-aligned, 2-way banks
  int bh = blockIdx.y, b = bh >> 3, h = bh & 7;
  int wid = threadIdx.x >> 6, lane = threadIdx.x & 63;
  int lr = lane & 15, g = lane >> 4, lk = g * 8;
  int r0 = blockIdx.x * 64 + wid * 16;
  float sscale2 = st[26], isa = st[21], cscale = st[22];
  v8bf aq0 = *(const v8bf*)(qs + ((size_t)bh * cS + r0 + lr) * cD + lk);
  v8bf aq1 = *(const v8bf*)(qs + ((size_t)bh * cS + r0 + lr) * cD + 32 + lk);
  float m2 = marr[bh * cS + r0 + lr];
  float fac = izarr[bh * cS + r0 + lr] * isa;
  const unsigned short* Kbase = ks + (size_t)bh * cS * cD;
  const unsigned short* Vbase = vT + (size_t)bh * cD * cS;

  v8bf K0[4], K1[4], V0[4], V1[4];
  f32x4 cacc[4] = {};

  auto loadK = [&](int kt) {
#pragma unroll
    for (int jc = 0; jc < 4; ++jc) {
      const unsigned short* p = Kbase + (size_t)(kt + jc * 16 + lr) * cD + lk;
      K0[jc] = *(const v8bf*)p; K1[jc] = *(const v8bf*)(p + 32);
    }
  };
  auto loadV = [&](int kt) {
#pragma unroll
    for (int dt = 0; dt < 4; ++dt) {
      const unsigned short* p = Vbase + (size_t)(dt * 16 + lr) * cS + kt + lk;
      V0[dt] = *(const v8bf*)p; V1[dt] = *(const v8bf*)(p + 32);
    }
  };
  // QK for tile kt (K regs already loaded) + softmax + packed P store into buffer bsel
  auto qk_store = [&](int bsel) {
#pragma unroll
    for (int jc = 0; jc < 4; ++jc) {
      f32x4 z = {0.f, 0.f, 0.f, 0.f};
      z = __builtin_amdgcn_mfma_f32_16x16x32_bf16(K0[jc], aq0, z, 0, 0, 0);
      z = __builtin_amdgcn_mfma_f32_16x16x32_bf16(K1[jc], aq1, z, 0, 0, 0);
      float a0 = fminf(rintf(__builtin_amdgcn_exp2f(__builtin_fmaf(z[0], sscale2, -m2)) * fac), 255.f);
      float a1 = fminf(rintf(__builtin_amdgcn_exp2f(__builtin_fmaf(z[1], sscale2, -m2)) * fac), 255.f);
      float a2 = fminf(rintf(__builtin_amdgcn_exp2f(__builtin_fmaf(z[2], sscale2, -m2)) * fac), 255.f);
      float a3 = fminf(rintf(__builtin_amdgcn_exp2f(__builtin_fmaf(z[3], sscale2, -m2)) * fac), 255.f);
      uint2 pw;
      pw.x = (__float_as_uint(a0) >> 16) | (__float_as_uint(a1) & 0xFFFF0000u);
      pw.y = (__float_as_uint(a2) >> 16) | (__float_as_uint(a3) & 0xFFFF0000u);
      *(uint2*)&plds[wid][bsel][lr][jc * 16 + g * 4] = pw;   // 4 consecutive k as one b64
    }
  };

  loadK(0);
  qk_store(0);
  loadK(64);
  loadV(0);
  int buf = 0;
  for (int kt = 64; kt < cS; kt += 64) {
    // PV for tile kt-64: P from plds[buf] (written last iter), V from regs
    v8bf ap0 = *(const v8bf*)&plds[wid][buf][lr][g * 8];
    v8bf ap1 = *(const v8bf*)&plds[wid][buf][lr][32 + g * 8];
#pragma unroll
    for (int dt = 0; dt < 4; ++dt) {
      cacc[dt] = __builtin_amdgcn_mfma_f32_16x16x32_bf16(ap0, V0[dt], cacc[dt], 0, 0, 0);
      cacc[dt] = __builtin_amdgcn_mfma_f32_16x16x32_bf16(ap1, V1[dt], cacc[dt], 0, 0, 0);
    }
    buf ^= 1;
    qk_store(buf);     // QK[kt] with K regs loaded last iter
    loadK(kt + 64);    // prefetch (last iter overshoots into vTb scratch — unused)
    loadV(kt);         // V for next iter's PV (WAR: V consumed above)
  }
  // epilogue: PV for the last tile
  {
    v8bf ap0 = *(const v8bf*)&plds[wid][buf][lr][g * 8];
    v8bf ap1 = *(const v8bf*)&plds[wid][buf][lr][32 + g * 8];
#pragma unroll
    for (int dt = 0; dt < 4; ++dt) {
      cacc[dt] = __builtin_amdgcn_mfma_f32_16x16x32_bf16(ap0, V0[dt], cacc[dt], 0, 0, 0);
      cacc[dt] = __builtin_amdgcn_mfma_f32_16x16x32_bf16(ap1, V1[dt], cacc[dt], 0, 0, 0);
    }
  }
  float lmax = 0.f;
#pragma unroll
  for (int dt = 0; dt < 4; ++dt)
#pragma unroll
    for (int r = 0; r < 4; ++r) {
      int qrow = r0 + g * 4 + r;
      int d = dt * 16 + lr;
      float val = cscale * cacc[dt][r];
      lmax = fmaxf(lmax, fabsf(val));
      ctx[((size_t)qrow * cB + b) * cE + h * cD + d] = val;  // [S][B][E]
    }
  lmax = wave_max(lmax);
  if (lane == 0) atomicMax(amax_slot, __float_as_uint(lmax));
}

// ---------------- launcher ----------------
extern "C" void kernel_launch(void* const* d_in, const int* in_sizes, int n_in, void* d_out,
                              int out_size, void* d_ws, size_t ws_size, hipStream_t stream) {
  (void)in_sizes; (void)n_in; (void)out_size; (void)ws_size;
  const float* x  = (const float*)d_in[0];
  const float* Wq = (const float*)d_in[1];
  const float* Wk = (const float*)d_in[2];
  const float* Wv = (const float*)d_in[3];
  const float* bq = (const float*)d_in[4];
  const float* bk = (const float*)d_in[5];
  const float* bv = (const float*)d_in[6];
  const float* Wo = (const float*)d_in[7];
  const float* bo = (const float*)d_in[8];
  float* out = (float*)d_out;

  char* ws = (char*)d_ws;
  size_t off = 0;
  auto alloc = [&](size_t bytes) { size_t o = off; off += (bytes + 255) & ~(size_t)255; return o; };
  float* st = (float*)(ws + alloc(64 * 4));
  unsigned short* xq  = (unsigned short*)(ws + alloc((size_t)cN * 2));
  unsigned short* wbq = (unsigned short*)(ws + alloc((size_t)cE * cE * 2));  // wbq..wbo contiguous
  unsigned short* wbk = (unsigned short*)(ws + alloc((size_t)cE * cE * 2));
  unsigned short* wbv = (unsigned short*)(ws + alloc((size_t)cE * cE * 2));
  unsigned short* wbo = (unsigned short*)(ws + alloc((size_t)cE * cE * 2));
  float* bfq = (float*)(ws + alloc(cE * 4));   // bfq..bfv contiguous
  float* bfk = (float*)(ws + alloc(cE * 4));
  float* bfv = (float*)(ws + alloc(cE * 4));
  float* bfo = (float*)(ws + alloc(cE * 4));
  float* qf = (float*)(ws + alloc((size_t)cN * 4));   // [BH][S][D]; qf,kf contiguous
  float* kf = (float*)(ws + alloc((size_t)cN * 4));
  float* vf = (float*)(ws + alloc((size_t)cN * 4));
  unsigned short* qsb = (unsigned short*)(ws + alloc((size_t)cN * 2));  // qsb,ksb contiguous
  unsigned short* ksb = (unsigned short*)(ws + alloc((size_t)cN * 2));
  unsigned short* vTb = (unsigned short*)(ws + alloc((size_t)cN * 2));
  float* marr  = (float*)(ws + alloc((size_t)cBH * cS * 4));
  float* izarr = (float*)(ws + alloc((size_t)cBH * cS * 4));
  float* ctxf = qf;                      // alias: qf dead after quant(q)
  unsigned short* cib = (unsigned short*)kf;  // alias: kf dead after quant(k)
  // total ws ~ 87 MB

  int n4 = cN / 4;
  int nw4 = cE * cE / 4;
  hipMemsetAsync(st, 0, 256, stream);
  absmax_kernel<<<1024, 256, 0, stream>>>(x, n4, (unsigned*)(st + 0));
  absmax4_kernel<<<dim3(64, 4), 256, 0, stream>>>(Wq, Wk, Wv, Wo, nw4, (unsigned*)(st + 1));
  scales_kernel<<<1, 1, 0, stream>>>(st, 0);
  quant_x_kernel<<<1024, 256, 0, stream>>>(x, xq, st, n4);
  quant_w4_kernel<<<dim3(64, 4), 256, 0, stream>>>(Wq, Wk, Wv, Wo, wbq, nw4, st);
  bias3_kernel<<<dim3(2, 3), 256, 0, stream>>>(bq, bk, bv, bfq, st);
  gemm_kernel<0><<<dim3(cSB / 64, cE / 64), 256, 0, stream>>>(xq, wbq, bfq, qf, st, 12, 13, (unsigned*)(st + 5));
  gemm_kernel<0><<<dim3(cSB / 64, cE / 64), 256, 0, stream>>>(xq, wbk, bfk, kf, st, 12, 14, (unsigned*)(st + 6));
  gemm_kernel<0><<<dim3(cSB / 64, cE / 64), 256, 0, stream>>>(xq, wbv, bfv, vf, st, 12, 15, (unsigned*)(st + 7));
  scales_kernel<<<1, 1, 0, stream>>>(st, 1);
  quant_qk_kernel<<<dim3(512, 2), 256, 0, stream>>>(qf, qsb, n4, st);
  quant_vT_kernel<<<dim3(cS / 64, cBH), 256, 0, stream>>>(vf, vTb, st);
  attn_pass1_kernel<<<dim3(cS / 64, cBH), 256, 0, stream>>>(qsb, ksb, marr, izarr, st, (unsigned*)(st + 8));
  scales_kernel<<<1, 1, 0, stream>>>(st, 2);
  attn_pass2_kernel<<<dim3(cS / 64, cBH), 256, 0, stream>>>(qsb, ksb, vTb, marr, izarr, ctxf, st, (unsigned*)(st + 9));
  scales_kernel<<<1, 1, 0, stream>>>(st, 3);
  quant_s8_kernel<<<1024, 256, 0, stream>>>(ctxf, cib, n4, st, 23, 1.0f);
  bias_kernel<<<2, 256, 0, stream>>>(bo, bfo, st, 23, 16);
  gemm_kernel<1><<<dim3(cSB / 64, cE / 64), 256, 0, stream>>>(cib, wbo, bfo, out, st, 23, 16, (unsigned*)(st + 10));
  scales_kernel<<<1, 1, 0, stream>>>(st, 4);
  final_quant_kernel<<<1024, 256, 0, stream>>>(out, st, n4);
}

// Round 8
// 574.467 us; speedup vs baseline: 1.3501x; 1.3501x over previous
//
#include <hip/hip_runtime.h>

// QuantMHSANet: Brevitas-style per-tensor fake-quant MHSA.
// S=2048 B=4 E=512 H=8 D=64. All GEMMs run as integer-exact bf16 MFMA.
constexpr int cS = 2048, cB = 4, cE = 512, cH = 8, cD = 64;
constexpr int cSB = cS * cB;   // 8192 rows
constexpr int cBH = cB * cH;   // 32 (b,h) pairs
constexpr int cN  = cSB * cE;  // 4194304 elements

typedef __bf16 v8bf  __attribute__((ext_vector_type(8)));
typedef float  f32x4 __attribute__((ext_vector_type(4)));

constexpr float cLOG2E = 1.4426950408889634f;

// ---- stat slots (float) ----
// 0 amax_x | 1..4 amax_w(q,k,v,o) | 5 amax_q 6 amax_k 7 amax_v | 8 max_invz
// 9 amax_ctx | 10 amax_y | 11 s0 | 12 s_in | 13..16 s_w(q,k,v,o) |
// 17 s_q 18 s_k 19 s_v | 20 scale_a 21 inv_scale_a 22 ctx_scale | 23 s_c | 24 s_y |
// 25 s_q*s_k | 26 s_q*s_k*log2e

// Quantized ints |v|<=255 have <=8 significand bits -> bf16 truncation is exact.
__device__ __forceinline__ unsigned short q2bf(float f) {
  return (unsigned short)(__float_as_uint(f) >> 16);
}
__device__ __forceinline__ float clip8(float t) { return fminf(fmaxf(t, -128.f), 127.f); }
__device__ __forceinline__ float wave_max(float v) {
#pragma unroll
  for (int o = 32; o > 0; o >>= 1) v = fmaxf(v, __shfl_down(v, o));
  return v;
}

// ---- cooperative async staging of one contiguous 8KB tile (64x64 bf16) ----
// global_load_lds: LDS dest = wave-uniform base + lane*16 (linear). The XOR chunk
// swizzle (chunk ^= row&7, 16B chunks, 8 chunks/row) is applied on the GLOBAL source
// address (rule #21: linear dest + inverse-swz source + swz on read). Involution.
__device__ __forceinline__ void stage8k(const unsigned short* __restrict__ gsrc,
                                        unsigned short* lds, int tid) {
  int w = tid >> 6;
#pragma unroll
  for (int is = 0; is < 2; ++is) {
    int c = is * 256 + tid;                              // dest chunk 0..511
    int cp = (c & ~7) | ((c & 7) ^ ((c >> 3) & 7));      // src chunk (self-inverse)
    const char* g = (const char*)gsrc + (size_t)cp * 16;
    char* l = (char*)lds + (size_t)(is * 4096 + w * 1024);  // wave-uniform base
    __builtin_amdgcn_global_load_lds(
        (const __attribute__((address_space(1))) unsigned int*)g,
        (__attribute__((address_space(3))) unsigned int*)l, 16, 0, 0);
  }
}
// swizzled b128 fragment read from a staged [64][64] bf16 tile
__device__ __forceinline__ v8bf lds_frag(const unsigned short* tile, int row, int chunk) {
  int sc = chunk ^ (row & 7);
  return *(const v8bf*)((const char*)tile + row * 128 + sc * 16);
}

// ---------------- reductions & scales ----------------
__global__ void absmax_kernel(const float* __restrict__ p, int n4, unsigned* slot) {
  int tid = blockIdx.x * blockDim.x + threadIdx.x, stride = gridDim.x * blockDim.x;
  float m = 0.f;
  for (int i = tid; i < n4; i += stride) {
    float4 v = ((const float4*)p)[i];
    m = fmaxf(m, fmaxf(fmaxf(fabsf(v.x), fabsf(v.y)), fmaxf(fabsf(v.z), fabsf(v.w))));
  }
  m = wave_max(m);
  __shared__ float sm[4];
  int lane = threadIdx.x & 63, wid = threadIdx.x >> 6;
  if (lane == 0) sm[wid] = m;
  __syncthreads();
  if (threadIdx.x == 0) {
    float mm = sm[0];
    for (int w = 1; w < (int)blockDim.x / 64; ++w) mm = fmaxf(mm, sm[w]);
    atomicMax(slot, __float_as_uint(mm));
  }
}

// 4 weight matrices in one launch (blockIdx.y selects)
__global__ void absmax4_kernel(const float* __restrict__ w0, const float* __restrict__ w1,
                               const float* __restrict__ w2, const float* __restrict__ w3,
                               int n4, unsigned* slots) {
  int y = blockIdx.y;
  const float* p = (y == 0) ? w0 : (y == 1) ? w1 : (y == 2) ? w2 : w3;
  int tid = blockIdx.x * blockDim.x + threadIdx.x, stride = gridDim.x * blockDim.x;
  float m = 0.f;
  for (int i = tid; i < n4; i += stride) {
    float4 v = ((const float4*)p)[i];
    m = fmaxf(m, fmaxf(fmaxf(fabsf(v.x), fabsf(v.y)), fmaxf(fabsf(v.z), fabsf(v.w))));
  }
  m = wave_max(m);
  __shared__ float sm[4];
  int lane = threadIdx.x & 63, wid = threadIdx.x >> 6;
  if (lane == 0) sm[wid] = m;
  __syncthreads();
  if (threadIdx.x == 0) {
    float mm = fmaxf(fmaxf(sm[0], sm[1]), fmaxf(sm[2], sm[3]));
    atomicMax(slots + y, __float_as_uint(mm));
  }
}

__global__ void scales_kernel(float* st, int stage) {
  if (stage == 0) {
    float s0 = fmaxf(st[0], 1e-8f) / 127.f;
    st[11] = s0;
    float mxq = s0 * 127.f;                 // max|xq| (max int is always 127)
    st[12] = fmaxf(mxq, 1e-8f) / 127.f;     // s_in
    for (int i = 0; i < 4; ++i) st[13 + i] = fmaxf(st[1 + i], 1e-8f) / 127.f;
  } else if (stage == 1) {
    st[17] = fmaxf(st[5] * 0.125f, 1e-8f) / 127.f;  // s_q (q/sqrt(64))
    st[18] = fmaxf(st[6], 1e-8f) / 127.f;           // s_k
    st[19] = fmaxf(st[7], 1e-8f) / 127.f;           // s_v
    st[25] = st[17] * st[18];
    st[26] = st[25] * cLOG2E;
  } else if (stage == 2) {
    float sa = fmaxf(st[8], 1e-8f) / 255.f;         // max(attn)=1/minZ
    st[20] = sa; st[21] = 1.f / sa; st[22] = sa * st[19];
  } else if (stage == 3) {
    st[23] = fmaxf(st[9], 1e-8f) / 127.f;           // s_c
  } else {
    st[24] = fmaxf(st[10], 1e-8f) / 127.f;          // s_y
  }
}

// ---------------- elementwise quantizers ----------------
__global__ void quant_x_kernel(const float* __restrict__ x, unsigned short* __restrict__ xq,
                               const float* st, int n4) {
  float s0 = st[11], si = st[12];
  int tid = blockIdx.x * blockDim.x + threadIdx.x, stride = gridDim.x * blockDim.x;
  for (int i = tid; i < n4; i += stride) {
    float4 v = ((const float4*)x)[i];
    ushort4 o; float t;
    t = s0 * clip8(rintf(v.x / s0)); o.x = q2bf(clip8(rintf(t / si)));
    t = s0 * clip8(rintf(v.y / s0)); o.y = q2bf(clip8(rintf(t / si)));
    t = s0 * clip8(rintf(v.z / s0)); o.z = q2bf(clip8(rintf(t / si)));
    t = s0 * clip8(rintf(v.w / s0)); o.w = q2bf(clip8(rintf(t / si)));
    ((ushort4*)xq)[i] = o;
  }
}

// 4 weight matrices quantized in one launch; outputs contiguous at outbase + y*cE*cE
__global__ void quant_w4_kernel(const float* __restrict__ w0, const float* __restrict__ w1,
                                const float* __restrict__ w2, const float* __restrict__ w3,
                                unsigned short* __restrict__ outbase, int n4, const float* st) {
  int y = blockIdx.y;
  const float* in = (y == 0) ? w0 : (y == 1) ? w1 : (y == 2) ? w2 : w3;
  unsigned short* outp = outbase + (size_t)y * cE * cE;
  float s = st[13 + y];
  int tid = blockIdx.x * blockDim.x + threadIdx.x, stride = gridDim.x * blockDim.x;
  for (int i = tid; i < n4; i += stride) {
    float4 v = ((const float4*)in)[i];
    ushort4 o;
    o.x = q2bf(clip8(rintf(v.x / s)));
    o.y = q2bf(clip8(rintf(v.y / s)));
    o.z = q2bf(clip8(rintf(v.z / s)));
    o.w = q2bf(clip8(rintf(v.w / s)));
    ((ushort4*)outp)[i] = o;
  }
}

__global__ void quant_s8_kernel(const float* __restrict__ in, unsigned short* __restrict__ outp,
                                int n4, const float* st, int slot, float premul) {
  float s = st[slot];
  int tid = blockIdx.x * blockDim.x + threadIdx.x, stride = gridDim.x * blockDim.x;
  for (int i = tid; i < n4; i += stride) {
    float4 v = ((const float4*)in)[i];
    ushort4 o;
    o.x = q2bf(clip8(rintf(v.x * premul / s)));
    o.y = q2bf(clip8(rintf(v.y * premul / s)));
    o.z = q2bf(clip8(rintf(v.z * premul / s)));
    o.w = q2bf(clip8(rintf(v.w * premul / s)));
    ((ushort4*)outp)[i] = o;
  }
}

// q and k quantized in one launch (blockIdx.y: 0=q premul 1/8 slot17, 1=k slot18)
__global__ void quant_qk_kernel(const float* __restrict__ qf, unsigned short* __restrict__ qsb,
                                int n4, const float* st) {
  int y = blockIdx.y;
  const float* in = qf + (size_t)y * cN;
  unsigned short* outp = qsb + (size_t)y * cN;
  float s = st[17 + y];
  float premul = y ? 1.0f : 0.125f;
  int tid = blockIdx.x * blockDim.x + threadIdx.x, stride = gridDim.x * blockDim.x;
  for (int i = tid; i < n4; i += stride) {
    float4 v = ((const float4*)in)[i];
    ushort4 o;
    o.x = q2bf(clip8(rintf(v.x * premul / s)));
    o.y = q2bf(clip8(rintf(v.y * premul / s)));
    o.z = q2bf(clip8(rintf(v.z * premul / s)));
    o.w = q2bf(clip8(rintf(v.w * premul / s)));
    ((ushort4*)outp)[i] = o;
  }
}

// q/k/v biases in one launch; outputs contiguous at bdst + y*512
__global__ void bias3_kernel(const float* __restrict__ b0, const float* __restrict__ b1,
                             const float* __restrict__ b2, float* __restrict__ bdst,
                             const float* st) {
  int y = blockIdx.y;
  const float* bsrc = (y == 0) ? b0 : (y == 1) ? b1 : b2;
  int f = blockIdx.x * blockDim.x + threadIdx.x;
  if (f < cE) {
    float s = st[12] * st[13 + y];
    bdst[y * cE + f] = s * rintf(bsrc[f] / s);
  }
}

__global__ void bias_kernel(const float* __restrict__ bsrc, float* __restrict__ bdst,
                            const float* st, int slot_in, int slot_w) {
  int f = blockIdx.x * blockDim.x + threadIdx.x;
  if (f < cE) {
    float s = st[slot_in] * st[slot_w];
    bdst[f] = s * rintf(bsrc[f] / s);   // int32 clip is a no-op at these magnitudes
  }
}

// V: [BH][S][D] f32 -> quantized, TILED transposed layout [bh][kt/64][d=64][s%64] bf16
// so each (bh, kt) V^T tile is one contiguous 8KB block for global_load_lds staging.
__global__ __launch_bounds__(256) void quant_vT_kernel(const float* __restrict__ v,
                                                       unsigned short* __restrict__ vT,
                                                       const float* st) {
  __shared__ unsigned short tile[64][65];
  int bh = blockIdx.y, bx = blockIdx.x, s0 = bx * 64;
  float sv = st[19];
  int td = threadIdx.x & 63, tr = threadIdx.x >> 6;
  for (int r = tr; r < 64; r += 4)
    tile[r][td] = q2bf(clip8(rintf(v[((size_t)bh * cS + s0 + r) * cD + td] / sv)));
  __syncthreads();
  for (int r = tr; r < 64; r += 4)
    vT[((size_t)(bh * 32 + bx) * 64 + r) * 64 + td] = tile[td][r];
}

__global__ void final_quant_kernel(float* __restrict__ y, const float* st, int n4) {
  float s = st[24];
  int tid = blockIdx.x * blockDim.x + threadIdx.x, stride = gridDim.x * blockDim.x;
  for (int i = tid; i < n4; i += stride) {
    float4 v = ((float4*)y)[i];
    v.x = s * clip8(rintf(v.x / s)); v.y = s * clip8(rintf(v.y / s));
    v.z = s * clip8(rintf(v.z / s)); v.w = s * clip8(rintf(v.w / s));
    ((float4*)y)[i] = v;
  }
}

// ---------------- integer-exact bf16 MFMA GEMM ----------------
// C[row,col] = sum_e A[row][e]*W[col][e]; both stored K-major (512 cols bf16-int).
// OUTMODE 0: write [B][H][S][D] (heads split) ; OUTMODE 1: write row-major [SB][E].
template <int OUTMODE>
__global__ __launch_bounds__(256) void gemm_kernel(const unsigned short* __restrict__ A,
                                                   const unsigned short* __restrict__ Wb,
                                                   const float* __restrict__ bias,
                                                   float* __restrict__ out, const float* st,
                                                   int slot_in, int slot_w, unsigned* amax_slot) {
  int wid = threadIdx.x >> 6, lane = threadIdx.x & 63;
  int wm = wid >> 1, wn = wid & 1;
  int row0 = blockIdx.x * 64 + wm * 32;
  int col0 = blockIdx.y * 64 + wn * 32;
  int lr = lane & 15, lk = (lane >> 4) * 8;
  f32x4 acc[2][2] = {};
  const unsigned short* a0p = A + (size_t)(row0 + lr) * cE + lk;
  const unsigned short* a1p = A + (size_t)(row0 + 16 + lr) * cE + lk;
  const unsigned short* b0p = Wb + (size_t)(col0 + lr) * cE + lk;
  const unsigned short* b1p = Wb + (size_t)(col0 + 16 + lr) * cE + lk;
  for (int e0 = 0; e0 < cE; e0 += 32) {
    v8bf a0 = *(const v8bf*)(a0p + e0), a1 = *(const v8bf*)(a1p + e0);
    v8bf b0 = *(const v8bf*)(b0p + e0), b1 = *(const v8bf*)(b1p + e0);
    acc[0][0] = __builtin_amdgcn_mfma_f32_16x16x32_bf16(a0, b0, acc[0][0], 0, 0, 0);
    acc[0][1] = __builtin_amdgcn_mfma_f32_16x16x32_bf16(a0, b1, acc[0][1], 0, 0, 0);
    acc[1][0] = __builtin_amdgcn_mfma_f32_16x16x32_bf16(a1, b0, acc[1][0], 0, 0, 0);
    acc[1][1] = __builtin_amdgcn_mfma_f32_16x16x32_bf16(a1, b1, acc[1][1], 0, 0, 0);
  }
  float scale = st[slot_in] * st[slot_w];
  float lmax = 0.f;
#pragma unroll
  for (int mi = 0; mi < 2; ++mi)
#pragma unroll
    for (int ni = 0; ni < 2; ++ni)
#pragma unroll
      for (int r = 0; r < 4; ++r) {
        int row = row0 + mi * 16 + (lane >> 4) * 4 + r;   // C/D: row=(l>>4)*4+reg
        int col = col0 + ni * 16 + lr;                    //      col=l&15
        float val = scale * acc[mi][ni][r] + bias[col];
        lmax = fmaxf(lmax, fabsf(val));
        if (OUTMODE == 0) {
          int s = row >> 2, bb = row & 3, h = col >> 6, d = col & 63;
          out[(((size_t)(bb * cH + h)) * cS + s) * cD + d] = val;
        } else {
          out[(size_t)row * cE + col] = val;
        }
      }
  lmax = wave_max(lmax);
  if (lane == 0) atomicMax(amax_slot, __float_as_uint(lmax));
}

// ---------------- attention pass 1: per-row (m2, 1/Z) in log2 domain ----------------
// Swapped QK (A=K frag, B=Q frag): lane owns q-row = lane&15, k = jc*16+(lane>>4)*4+r.
// K tiles staged cooperatively in LDS (async global_load_lds, double-buffered,
// 2-phase: issue t+1, compute t, barrier). Per-lane online softmax; end merge.
__global__ __launch_bounds__(256) void attn_pass1_kernel(const unsigned short* __restrict__ qs,
                                                         const unsigned short* __restrict__ ks,
                                                         float* __restrict__ marr,
                                                         float* __restrict__ izarr,
                                                         const float* st, unsigned* maxiz_slot) {
  __shared__ __align__(16) unsigned short kbuf[2][64][64];
  int tid = threadIdx.x;
  int bh = blockIdx.y;
  int wid = tid >> 6, lane = tid & 63;
  int lr = lane & 15, g = lane >> 4, lk = g * 8;
  int r0 = blockIdx.x * 64 + wid * 16;
  float sscale2 = st[26];   // s_q*s_k*log2e  (log2-domain scores)
  v8bf aq0 = *(const v8bf*)(qs + ((size_t)bh * cS + r0 + lr) * cD + lk);
  v8bf aq1 = *(const v8bf*)(qs + ((size_t)bh * cS + r0 + lr) * cD + 32 + lk);
  const unsigned short* Kb = ks + (size_t)bh * cS * cD;   // 64-row tile t at Kb + t*4096

  stage8k(Kb, &kbuf[0][0][0], tid);
  __syncthreads();                       // drains vmcnt -> tile 0 ready
  float pm = -1e30f, zs = 0.f;
  int buf = 0;
  for (int t = 0; t < 32; ++t) {
    if (t < 31) stage8k(Kb + (size_t)(t + 1) * 4096, &kbuf[buf ^ 1][0][0], tid);
    const unsigned short* Kt = &kbuf[buf][0][0];
    f32x4 s4[4];
#pragma unroll
    for (int jc = 0; jc < 4; ++jc) {
      v8bf k0 = lds_frag(Kt, jc * 16 + lr, g);
      v8bf k1 = lds_frag(Kt, jc * 16 + lr, g + 4);
      f32x4 z = {0.f, 0.f, 0.f, 0.f};
      z = __builtin_amdgcn_mfma_f32_16x16x32_bf16(k0, aq0, z, 0, 0, 0);
      z = __builtin_amdgcn_mfma_f32_16x16x32_bf16(k1, aq1, z, 0, 0, 0);
      s4[jc] = z;
    }
    float tv[16];
#pragma unroll
    for (int jc = 0; jc < 4; ++jc)
#pragma unroll
      for (int r = 0; r < 4; ++r) tv[jc * 4 + r] = s4[jc][r] * sscale2;
    float tm = tv[0];
#pragma unroll
    for (int i = 1; i < 16; ++i) tm = fmaxf(tm, tv[i]);
    float nm = fmaxf(pm, tm);
    float acc = zs * __builtin_amdgcn_exp2f(pm - nm);
#pragma unroll
    for (int i = 0; i < 16; ++i) acc += __builtin_amdgcn_exp2f(tv[i] - nm);
    zs = acc; pm = nm;
    __syncthreads();                     // next tile staged + kbuf[buf] free
    buf ^= 1;
  }
  // merge the 4 groups (lanes lr, lr+16, lr+32, lr+48)
#pragma unroll
  for (int o = 16; o < 64; o <<= 1) {
    float mo = __shfl_xor(pm, o);
    float zo = __shfl_xor(zs, o);
    float nm = fmaxf(pm, mo);
    zs = zs * __builtin_amdgcn_exp2f(pm - nm) + zo * __builtin_amdgcn_exp2f(mo - nm);
    pm = nm;
  }
  float iz = 1.0f / zs;
  if (g == 0) {
    marr[bh * cS + r0 + lr] = pm;    // log2-domain row max
    izarr[bh * cS + r0 + lr] = iz;
  }
  float wmax = wave_max(iz);
  if (lane == 0) atomicMax(maxiz_slot, __float_as_uint(wmax));
}

// ---------------- attention pass 2: P=u8-quant(softmax) ; ctx += P*V ----------------
// K and V^T tiles staged cooperatively (async global_load_lds, dbuf, 2-phase).
// Swapped QK + per-lane softmax + packed b64 P-store through wave-private plds
// (single buffer; same-wave DS ordering covers write->read). One barrier/iter.
__global__ __launch_bounds__(256) void attn_pass2_kernel(
    const unsigned short* __restrict__ qs, const unsigned short* __restrict__ ks,
    const unsigned short* __restrict__ vT, const float* __restrict__ marr,
    const float* __restrict__ izarr, float* __restrict__ ctx, const float* st,
    unsigned* amax_slot) {
  __shared__ __align__(16) unsigned short kbuf[2][64][64];
  __shared__ __align__(16) unsigned short vbuf[2][64][64];
  __shared__ __align__(16) unsigned short plds[4][16][88];
  int tid = threadIdx.x;
  int bh = blockIdx.y, b = bh >> 3, h = bh & 7;
  int wid = tid >> 6, lane = tid & 63;
  int lr = lane & 15, g = lane >> 4, lk = g * 8;
  int r0 = blockIdx.x * 64 + wid * 16;
  float sscale2 = st[26], isa = st[21], cscale = st[22];
  v8bf aq0 = *(const v8bf*)(qs + ((size_t)bh * cS + r0 + lr) * cD + lk);
  v8bf aq1 = *(const v8bf*)(qs + ((size_t)bh * cS + r0 + lr) * cD + 32 + lk);
  float m2 = marr[bh * cS + r0 + lr];
  float fac = izarr[bh * cS + r0 + lr] * isa;
  const unsigned short* Kb = ks + (size_t)bh * cS * cD;      // K tile t at +t*4096
  const unsigned short* Vb = vT + (size_t)bh * 32 * 4096;    // V^T tile t at +t*4096
  f32x4 cacc[4] = {};

  stage8k(Kb, &kbuf[0][0][0], tid);
  stage8k(Vb, &vbuf[0][0][0], tid);
  __syncthreads();
  int buf = 0;
  for (int t = 0; t < 32; ++t) {
    if (t < 31) {
      stage8k(Kb + (size_t)(t + 1) * 4096, &kbuf[buf ^ 1][0][0], tid);
      stage8k(Vb + (size_t)(t + 1) * 4096, &vbuf[buf ^ 1][0][0], tid);
    }
    const unsigned short* Kt = &kbuf[buf][0][0];
    const unsigned short* Vt = &vbuf[buf][0][0];
    // QK + softmax + packed P store
#pragma unroll
    for (int jc = 0; jc < 4; ++jc) {
      v8bf k0 = lds_frag(Kt, jc * 16 + lr, g);
      v8bf k1 = lds_frag(Kt, jc * 16 + lr, g + 4);
      f32x4 z = {0.f, 0.f, 0.f, 0.f};
      z = __builtin_amdgcn_mfma_f32_16x16x32_bf16(k0, aq0, z, 0, 0, 0);
      z = __builtin_amdgcn_mfma_f32_16x16x32_bf16(k1, aq1, z, 0, 0, 0);
      float a0 = fminf(rintf(__builtin_amdgcn_exp2f(__builtin_fmaf(z[0], sscale2, -m2)) * fac), 255.f);
      float a1 = fminf(rintf(__builtin_amdgcn_exp2f(__builtin_fmaf(z[1], sscale2, -m2)) * fac), 255.f);
      float a2 = fminf(rintf(__builtin_amdgcn_exp2f(__builtin_fmaf(z[2], sscale2, -m2)) * fac), 255.f);
      float a3 = fminf(rintf(__builtin_amdgcn_exp2f(__builtin_fmaf(z[3], sscale2, -m2)) * fac), 255.f);
      uint2 pw;
      pw.x = (__float_as_uint(a0) >> 16) | (__float_as_uint(a1) & 0xFFFF0000u);
      pw.y = (__float_as_uint(a2) >> 16) | (__float_as_uint(a3) & 0xFFFF0000u);
      *(uint2*)&plds[wid][lr][jc * 16 + g * 4] = pw;   // 4 consecutive k as one b64
    }
    // PV (same-wave DS ordering: plds writes complete before these reads)
    v8bf ap0 = *(const v8bf*)&plds[wid][lr][lk];
    v8bf ap1 = *(const v8bf*)&plds[wid][lr][32 + lk];
#pragma unroll
    for (int dt = 0; dt < 4; ++dt) {
      v8bf v0 = lds_frag(Vt, dt * 16 + lr, g);
      v8bf v1 = lds_frag(Vt, dt * 16 + lr, g + 4);
      cacc[dt] = __builtin_amdgcn_mfma_f32_16x16x32_bf16(ap0, v0, cacc[dt], 0, 0, 0);
      cacc[dt] = __builtin_amdgcn_mfma_f32_16x16x32_bf16(ap1, v1, cacc[dt], 0, 0, 0);
    }
    __syncthreads();                     // next tiles staged + bufs free
    buf ^= 1;
  }
  float lmax = 0.f;
#pragma unroll
  for (int dt = 0; dt < 4; ++dt)
#pragma unroll
    for (int r = 0; r < 4; ++r) {
      int qrow = r0 + g * 4 + r;
      int d = dt * 16 + lr;
      float val = cscale * cacc[dt][r];
      lmax = fmaxf(lmax, fabsf(val));
      ctx[((size_t)qrow * cB + b) * cE + h * cD + d] = val;  // [S][B][E]
    }
  lmax = wave_max(lmax);
  if (lane == 0) atomicMax(amax_slot, __float_as_uint(lmax));
}

// ---------------- launcher ----------------
extern "C" void kernel_launch(void* const* d_in, const int* in_sizes, int n_in, void* d_out,
                              int out_size, void* d_ws, size_t ws_size, hipStream_t stream) {
  (void)in_sizes; (void)n_in; (void)out_size; (void)ws_size;
  const float* x  = (const float*)d_in[0];
  const float* Wq = (const float*)d_in[1];
  const float* Wk = (const float*)d_in[2];
  const float* Wv = (const float*)d_in[3];
  const float* bq = (const float*)d_in[4];
  const float* bk = (const float*)d_in[5];
  const float* bv = (const float*)d_in[6];
  const float* Wo = (const float*)d_in[7];
  const float* bo = (const float*)d_in[8];
  float* out = (float*)d_out;

  char* ws = (char*)d_ws;
  size_t off = 0;
  auto alloc = [&](size_t bytes) { size_t o = off; off += (bytes + 255) & ~(size_t)255; return o; };
  float* st = (float*)(ws + alloc(64 * 4));
  unsigned short* xq  = (unsigned short*)(ws + alloc((size_t)cN * 2));
  unsigned short* wbq = (unsigned short*)(ws + alloc((size_t)cE * cE * 2));  // wbq..wbo contiguous
  unsigned short* wbk = (unsigned short*)(ws + alloc((size_t)cE * cE * 2));
  unsigned short* wbv = (unsigned short*)(ws + alloc((size_t)cE * cE * 2));
  unsigned short* wbo = (unsigned short*)(ws + alloc((size_t)cE * cE * 2));
  float* bfq = (float*)(ws + alloc(cE * 4));   // bfq..bfv contiguous
  float* bfk = (float*)(ws + alloc(cE * 4));
  float* bfv = (float*)(ws + alloc(cE * 4));
  float* bfo = (float*)(ws + alloc(cE * 4));
  float* qf = (float*)(ws + alloc((size_t)cN * 4));   // [BH][S][D]; qf,kf contiguous
  float* kf = (float*)(ws + alloc((size_t)cN * 4));
  float* vf = (float*)(ws + alloc((size_t)cN * 4));
  unsigned short* qsb = (unsigned short*)(ws + alloc((size_t)cN * 2));  // qsb,ksb contiguous
  unsigned short* ksb = (unsigned short*)(ws + alloc((size_t)cN * 2));
  unsigned short* vTb = (unsigned short*)(ws + alloc((size_t)cN * 2));
  float* marr  = (float*)(ws + alloc((size_t)cBH * cS * 4));
  float* izarr = (float*)(ws + alloc((size_t)cBH * cS * 4));
  float* ctxf = qf;                      // alias: qf dead after quant(q)
  unsigned short* cib = (unsigned short*)kf;  // alias: kf dead after quant(k)
  // total ws ~ 87 MB

  int n4 = cN / 4;
  int nw4 = cE * cE / 4;
  hipMemsetAsync(st, 0, 256, stream);
  absmax_kernel<<<1024, 256, 0, stream>>>(x, n4, (unsigned*)(st + 0));
  absmax4_kernel<<<dim3(64, 4), 256, 0, stream>>>(Wq, Wk, Wv, Wo, nw4, (unsigned*)(st + 1));
  scales_kernel<<<1, 1, 0, stream>>>(st, 0);
  quant_x_kernel<<<1024, 256, 0, stream>>>(x, xq, st, n4);
  quant_w4_kernel<<<dim3(64, 4), 256, 0, stream>>>(Wq, Wk, Wv, Wo, wbq, nw4, st);
  bias3_kernel<<<dim3(2, 3), 256, 0, stream>>>(bq, bk, bv, bfq, st);
  gemm_kernel<0><<<dim3(cSB / 64, cE / 64), 256, 0, stream>>>(xq, wbq, bfq, qf, st, 12, 13, (unsigned*)(st + 5));
  gemm_kernel<0><<<dim3(cSB / 64, cE / 64), 256, 0, stream>>>(xq, wbk, bfk, kf, st, 12, 14, (unsigned*)(st + 6));
  gemm_kernel<0><<<dim3(cSB / 64, cE / 64), 256, 0, stream>>>(xq, wbv, bfv, vf, st, 12, 15, (unsigned*)(st + 7));
  scales_kernel<<<1, 1, 0, stream>>>(st, 1);
  quant_qk_kernel<<<dim3(512, 2), 256, 0, stream>>>(qf, qsb, n4, st);
  quant_vT_kernel<<<dim3(cS / 64, cBH), 256, 0, stream>>>(vf, vTb, st);
  attn_pass1_kernel<<<dim3(cS / 64, cBH), 256, 0, stream>>>(qsb, ksb, marr, izarr, st, (unsigned*)(st + 8));
  scales_kernel<<<1, 1, 0, stream>>>(st, 2);
  attn_pass2_kernel<<<dim3(cS / 64, cBH), 256, 0, stream>>>(qsb, ksb, vTb, marr, izarr, ctxf, st, (unsigned*)(st + 9));
  scales_kernel<<<1, 1, 0, stream>>>(st, 3);
  quant_s8_kernel<<<1024, 256, 0, stream>>>(ctxf, cib, n4, st, 23, 1.0f);
  bias_kernel<<<2, 256, 0, stream>>>(bo, bfo, st, 23, 16);
  gemm_kernel<1><<<dim3(cSB / 64, cE / 64), 256, 0, stream>>>(cib, wbo, bfo, out, st, 23, 16, (unsigned*)(st + 10));
  scales_kernel<<<1, 1, 0, stream>>>(st, 4);
  final_quant_kernel<<<1024, 256, 0, stream>>>(out, st, n4);
}

// Round 10
// 534.961 us; speedup vs baseline: 1.4498x; 1.0738x over previous
//
#include <hip/hip_runtime.h>

// QuantMHSANet: Brevitas-style per-tensor fake-quant MHSA.
// S=2048 B=4 E=512 H=8 D=64. All GEMMs run as integer-exact bf16 MFMA.
constexpr int cS = 2048, cB = 4, cE = 512, cH = 8, cD = 64;
constexpr int cSB = cS * cB;   // 8192 rows
constexpr int cBH = cB * cH;   // 32 (b,h) pairs
constexpr int cN  = cSB * cE;  // 4194304 elements

typedef __bf16 v8bf  __attribute__((ext_vector_type(8)));
typedef float  f32x4 __attribute__((ext_vector_type(4)));

constexpr float cLOG2E = 1.4426950408889634f;

// ---- stat slots (float) ----
// 0 amax_x | 1..4 amax_w(q,k,v,o) | 5 amax_q 6 amax_k 7 amax_v | 8 max_invz
// 9 amax_ctx | 10 amax_y | 11 s0 | 12 s_in | 13..16 s_w(q,k,v,o) |
// 17 s_q 18 s_k 19 s_v | 20 scale_a 21 inv_scale_a 22 ctx_scale | 23 s_c | 24 s_y |
// 25 s_q*s_k | 26 s_q*s_k*log2e

// Quantized ints |v|<=255 have <=8 significand bits -> bf16 truncation is exact.
__device__ __forceinline__ unsigned short q2bf(float f) {
  return (unsigned short)(__float_as_uint(f) >> 16);
}
__device__ __forceinline__ float clip8(float t) { return fminf(fmaxf(t, -128.f), 127.f); }
__device__ __forceinline__ float wave_max(float v) {
#pragma unroll
  for (int o = 32; o > 0; o >>= 1) v = fmaxf(v, __shfl_down(v, o));
  return v;
}

// ---- cooperative async staging of one contiguous 8KB tile (64x64 bf16) ----
// global_load_lds: LDS dest = wave-uniform base + lane*16 (linear). The XOR chunk
// swizzle (chunk ^= row&7, 16B chunks, 8 chunks/row) is applied on the GLOBAL source
// address (rule #21: linear dest + inverse-swz source + swz on read). Involution.
__device__ __forceinline__ void stage8k(const unsigned short* __restrict__ gsrc,
                                        unsigned short* lds, int tid) {
  int w = tid >> 6;
#pragma unroll
  for (int is = 0; is < 2; ++is) {
    int c = is * 256 + tid;                              // dest chunk 0..511
    int cp = (c & ~7) | ((c & 7) ^ ((c >> 3) & 7));      // src chunk (self-inverse)
    const char* g = (const char*)gsrc + (size_t)cp * 16;
    char* l = (char*)lds + (size_t)(is * 4096 + w * 1024);  // wave-uniform base
    __builtin_amdgcn_global_load_lds(
        (const __attribute__((address_space(1))) unsigned int*)g,
        (__attribute__((address_space(3))) unsigned int*)l, 16, 0, 0);
  }
}
// swizzled b128 fragment read from a staged [64][64] bf16 tile
__device__ __forceinline__ v8bf lds_frag(const unsigned short* tile, int row, int chunk) {
  int sc = chunk ^ (row & 7);
  return *(const v8bf*)((const char*)tile + row * 128 + sc * 16);
}

// ---------------- reductions & scales ----------------
__global__ void absmax_kernel(const float* __restrict__ p, int n4, unsigned* slot) {
  int tid = blockIdx.x * blockDim.x + threadIdx.x, stride = gridDim.x * blockDim.x;
  float m = 0.f;
  for (int i = tid; i < n4; i += stride) {
    float4 v = ((const float4*)p)[i];
    m = fmaxf(m, fmaxf(fmaxf(fabsf(v.x), fabsf(v.y)), fmaxf(fabsf(v.z), fabsf(v.w))));
  }
  m = wave_max(m);
  __shared__ float sm[4];
  int lane = threadIdx.x & 63, wid = threadIdx.x >> 6;
  if (lane == 0) sm[wid] = m;
  __syncthreads();
  if (threadIdx.x == 0) {
    float mm = sm[0];
    for (int w = 1; w < (int)blockDim.x / 64; ++w) mm = fmaxf(mm, sm[w]);
    atomicMax(slot, __float_as_uint(mm));
  }
}

// 4 weight matrices in one launch (blockIdx.y selects)
__global__ void absmax4_kernel(const float* __restrict__ w0, const float* __restrict__ w1,
                               const float* __restrict__ w2, const float* __restrict__ w3,
                               int n4, unsigned* slots) {
  int y = blockIdx.y;
  const float* p = (y == 0) ? w0 : (y == 1) ? w1 : (y == 2) ? w2 : w3;
  int tid = blockIdx.x * blockDim.x + threadIdx.x, stride = gridDim.x * blockDim.x;
  float m = 0.f;
  for (int i = tid; i < n4; i += stride) {
    float4 v = ((const float4*)p)[i];
    m = fmaxf(m, fmaxf(fmaxf(fabsf(v.x), fabsf(v.y)), fmaxf(fabsf(v.z), fabsf(v.w))));
  }
  m = wave_max(m);
  __shared__ float sm[4];
  int lane = threadIdx.x & 63, wid = threadIdx.x >> 6;
  if (lane == 0) sm[wid] = m;
  __syncthreads();
  if (threadIdx.x == 0) {
    float mm = fmaxf(fmaxf(sm[0], sm[1]), fmaxf(sm[2], sm[3]));
    atomicMax(slots + y, __float_as_uint(mm));
  }
}

__global__ void scales_kernel(float* st, int stage) {
  if (stage == 0) {
    float s0 = fmaxf(st[0], 1e-8f) / 127.f;
    st[11] = s0;
    float mxq = s0 * 127.f;                 // max|xq| (max int is always 127)
    st[12] = fmaxf(mxq, 1e-8f) / 127.f;     // s_in
    for (int i = 0; i < 4; ++i) st[13 + i] = fmaxf(st[1 + i], 1e-8f) / 127.f;
  } else if (stage == 1) {
    st[17] = fmaxf(st[5] * 0.125f, 1e-8f) / 127.f;  // s_q (q/sqrt(64))
    st[18] = fmaxf(st[6], 1e-8f) / 127.f;           // s_k
    st[19] = fmaxf(st[7], 1e-8f) / 127.f;           // s_v
    st[25] = st[17] * st[18];
    st[26] = st[25] * cLOG2E;
  } else if (stage == 2) {
    float sa = fmaxf(st[8], 1e-8f) / 255.f;         // max(attn)=1/minZ
    st[20] = sa; st[21] = 1.f / sa; st[22] = sa * st[19];
  } else if (stage == 3) {
    st[23] = fmaxf(st[9], 1e-8f) / 127.f;           // s_c
  } else {
    st[24] = fmaxf(st[10], 1e-8f) / 127.f;          // s_y
  }
}

// ---------------- elementwise quantizers ----------------
__global__ void quant_x_kernel(const float* __restrict__ x, unsigned short* __restrict__ xq,
                               const float* st, int n4) {
  float s0 = st[11], si = st[12];
  int tid = blockIdx.x * blockDim.x + threadIdx.x, stride = gridDim.x * blockDim.x;
  for (int i = tid; i < n4; i += stride) {
    float4 v = ((const float4*)x)[i];
    ushort4 o; float t;
    t = s0 * clip8(rintf(v.x / s0)); o.x = q2bf(clip8(rintf(t / si)));
    t = s0 * clip8(rintf(v.y / s0)); o.y = q2bf(clip8(rintf(t / si)));
    t = s0 * clip8(rintf(v.z / s0)); o.z = q2bf(clip8(rintf(t / si)));
    t = s0 * clip8(rintf(v.w / s0)); o.w = q2bf(clip8(rintf(t / si)));
    ((ushort4*)xq)[i] = o;
  }
}

// 4 weight matrices quantized in one launch; outputs contiguous at outbase + y*cE*cE
__global__ void quant_w4_kernel(const float* __restrict__ w0, const float* __restrict__ w1,
                                const float* __restrict__ w2, const float* __restrict__ w3,
                                unsigned short* __restrict__ outbase, int n4, const float* st) {
  int y = blockIdx.y;
  const float* in = (y == 0) ? w0 : (y == 1) ? w1 : (y == 2) ? w2 : w3;
  unsigned short* outp = outbase + (size_t)y * cE * cE;
  float s = st[13 + y];
  int tid = blockIdx.x * blockDim.x + threadIdx.x, stride = gridDim.x * blockDim.x;
  for (int i = tid; i < n4; i += stride) {
    float4 v = ((const float4*)in)[i];
    ushort4 o;
    o.x = q2bf(clip8(rintf(v.x / s)));
    o.y = q2bf(clip8(rintf(v.y / s)));
    o.z = q2bf(clip8(rintf(v.z / s)));
    o.w = q2bf(clip8(rintf(v.w / s)));
    ((ushort4*)outp)[i] = o;
  }
}

__global__ void quant_s8_kernel(const float* __restrict__ in, unsigned short* __restrict__ outp,
                                int n4, const float* st, int slot, float premul) {
  float s = st[slot];
  int tid = blockIdx.x * blockDim.x + threadIdx.x, stride = gridDim.x * blockDim.x;
  for (int i = tid; i < n4; i += stride) {
    float4 v = ((const float4*)in)[i];
    ushort4 o;
    o.x = q2bf(clip8(rintf(v.x * premul / s)));
    o.y = q2bf(clip8(rintf(v.y * premul / s)));
    o.z = q2bf(clip8(rintf(v.z * premul / s)));
    o.w = q2bf(clip8(rintf(v.w * premul / s)));
    ((ushort4*)outp)[i] = o;
  }
}

// q and k quantized in one launch (blockIdx.y: 0=q premul 1/8 slot17, 1=k slot18)
__global__ void quant_qk_kernel(const float* __restrict__ qf, unsigned short* __restrict__ qsb,
                                int n4, const float* st) {
  int y = blockIdx.y;
  const float* in = qf + (size_t)y * cN;
  unsigned short* outp = qsb + (size_t)y * cN;
  float s = st[17 + y];
  float premul = y ? 1.0f : 0.125f;
  int tid = blockIdx.x * blockDim.x + threadIdx.x, stride = gridDim.x * blockDim.x;
  for (int i = tid; i < n4; i += stride) {
    float4 v = ((const float4*)in)[i];
    ushort4 o;
    o.x = q2bf(clip8(rintf(v.x * premul / s)));
    o.y = q2bf(clip8(rintf(v.y * premul / s)));
    o.z = q2bf(clip8(rintf(v.z * premul / s)));
    o.w = q2bf(clip8(rintf(v.w * premul / s)));
    ((ushort4*)outp)[i] = o;
  }
}

// q/k/v biases in one launch; outputs contiguous at bdst + y*512
__global__ void bias3_kernel(const float* __restrict__ b0, const float* __restrict__ b1,
                             const float* __restrict__ b2, float* __restrict__ bdst,
                             const float* st) {
  int y = blockIdx.y;
  const float* bsrc = (y == 0) ? b0 : (y == 1) ? b1 : b2;
  int f = blockIdx.x * blockDim.x + threadIdx.x;
  if (f < cE) {
    float s = st[12] * st[13 + y];
    bdst[y * cE + f] = s * rintf(bsrc[f] / s);
  }
}

__global__ void bias_kernel(const float* __restrict__ bsrc, float* __restrict__ bdst,
                            const float* st, int slot_in, int slot_w) {
  int f = blockIdx.x * blockDim.x + threadIdx.x;
  if (f < cE) {
    float s = st[slot_in] * st[slot_w];
    bdst[f] = s * rintf(bsrc[f] / s);   // int32 clip is a no-op at these magnitudes
  }
}

// V: [BH][S][D] f32 -> quantized, TILED transposed layout [bh][kt/64][d=64][s%64] bf16
// so each (bh, kt) V^T tile is one contiguous 8KB block for global_load_lds staging.
__global__ __launch_bounds__(256) void quant_vT_kernel(const float* __restrict__ v,
                                                       unsigned short* __restrict__ vT,
                                                       const float* st) {
  __shared__ unsigned short tile[64][65];
  int bh = blockIdx.y, bx = blockIdx.x, s0 = bx * 64;
  float sv = st[19];
  int td = threadIdx.x & 63, tr = threadIdx.x >> 6;
  for (int r = tr; r < 64; r += 4)
    tile[r][td] = q2bf(clip8(rintf(v[((size_t)bh * cS + s0 + r) * cD + td] / sv)));
  __syncthreads();
  for (int r = tr; r < 64; r += 4)
    vT[((size_t)(bh * 32 + bx) * 64 + r) * 64 + td] = tile[td][r];
}

__global__ void final_quant_kernel(float* __restrict__ y, const float* st, int n4) {
  float s = st[24];
  int tid = blockIdx.x * blockDim.x + threadIdx.x, stride = gridDim.x * blockDim.x;
  for (int i = tid; i < n4; i += stride) {
    float4 v = ((float4*)y)[i];
    v.x = s * clip8(rintf(v.x / s)); v.y = s * clip8(rintf(v.y / s));
    v.z = s * clip8(rintf(v.z / s)); v.w = s * clip8(rintf(v.w / s));
    ((float4*)y)[i] = v;
  }
}

// ---------------- integer-exact bf16 MFMA GEMM ----------------
// C[row,col] = sum_e A[row][e]*W[col][e]; both stored K-major (512 cols bf16-int).
// OUTMODE 0: write [B][H][S][D] (heads split) ; OUTMODE 1: write row-major [SB][E].
template <int OUTMODE>
__global__ __launch_bounds__(256) void gemm_kernel(const unsigned short* __restrict__ A,
                                                   const unsigned short* __restrict__ Wb,
                                                   const float* __restrict__ bias,
                                                   float* __restrict__ out, const float* st,
                                                   int slot_in, int slot_w, unsigned* amax_slot) {
  int wid = threadIdx.x >> 6, lane = threadIdx.x & 63;
  int wm = wid >> 1, wn = wid & 1;
  int row0 = blockIdx.x * 64 + wm * 32;
  int col0 = blockIdx.y * 64 + wn * 32;
  int lr = lane & 15, lk = (lane >> 4) * 8;
  f32x4 acc[2][2] = {};
  const unsigned short* a0p = A + (size_t)(row0 + lr) * cE + lk;
  const unsigned short* a1p = A + (size_t)(row0 + 16 + lr) * cE + lk;
  const unsigned short* b0p = Wb + (size_t)(col0 + lr) * cE + lk;
  const unsigned short* b1p = Wb + (size_t)(col0 + 16 + lr) * cE + lk;
  for (int e0 = 0; e0 < cE; e0 += 32) {
    v8bf a0 = *(const v8bf*)(a0p + e0), a1 = *(const v8bf*)(a1p + e0);
    v8bf b0 = *(const v8bf*)(b0p + e0), b1 = *(const v8bf*)(b1p + e0);
    acc[0][0] = __builtin_amdgcn_mfma_f32_16x16x32_bf16(a0, b0, acc[0][0], 0, 0, 0);
    acc[0][1] = __builtin_amdgcn_mfma_f32_16x16x32_bf16(a0, b1, acc[0][1], 0, 0, 0);
    acc[1][0] = __builtin_amdgcn_mfma_f32_16x16x32_bf16(a1, b0, acc[1][0], 0, 0, 0);
    acc[1][1] = __builtin_amdgcn_mfma_f32_16x16x32_bf16(a1, b1, acc[1][1], 0, 0, 0);
  }
  float scale = st[slot_in] * st[slot_w];
  float lmax = 0.f;
#pragma unroll
  for (int mi = 0; mi < 2; ++mi)
#pragma unroll
    for (int ni = 0; ni < 2; ++ni)
#pragma unroll
      for (int r = 0; r < 4; ++r) {
        int row = row0 + mi * 16 + (lane >> 4) * 4 + r;   // C/D: row=(l>>4)*4+reg
        int col = col0 + ni * 16 + lr;                    //      col=l&15
        float val = scale * acc[mi][ni][r] + bias[col];
        lmax = fmaxf(lmax, fabsf(val));
        if (OUTMODE == 0) {
          int s = row >> 2, bb = row & 3, h = col >> 6, d = col & 63;
          out[(((size_t)(bb * cH + h)) * cS + s) * cD + d] = val;
        } else {
          out[(size_t)row * cE + col] = val;
        }
      }
  lmax = wave_max(lmax);
  if (lane == 0) atomicMax(amax_slot, __float_as_uint(lmax));
}

// ---------------- attention pass 1: per-row (m2, 1/Z) in log2 domain ----------------
// Swapped QK (A=K frag, B=Q frag); 32 q-rows per wave (2 q-groups of 16) so each
// staged K tile is amortized over 2x MFMA work; K frag read once per jc, used by
// both groups. K tiles staged via async global_load_lds, dbuf, 2-phase.
__global__ __launch_bounds__(256) void attn_pass1_kernel(const unsigned short* __restrict__ qs,
                                                         const unsigned short* __restrict__ ks,
                                                         float* __restrict__ marr,
                                                         float* __restrict__ izarr,
                                                         const float* st, unsigned* maxiz_slot) {
  __shared__ __align__(16) unsigned short kbuf[2][64][64];
  int tid = threadIdx.x;
  int bh = blockIdx.y;
  int wid = tid >> 6, lane = tid & 63;
  int lr = lane & 15, g = lane >> 4, lk = g * 8;
  int r0 = blockIdx.x * 128 + wid * 32;
  float sscale2 = st[26];   // s_q*s_k*log2e  (log2-domain scores)
  v8bf aq0[2], aq1[2];
#pragma unroll
  for (int qg = 0; qg < 2; ++qg) {
    const unsigned short* qp = qs + ((size_t)bh * cS + r0 + qg * 16 + lr) * cD + lk;
    aq0[qg] = *(const v8bf*)qp; aq1[qg] = *(const v8bf*)(qp + 32);
  }
  const unsigned short* Kb = ks + (size_t)bh * cS * cD;   // 64-row tile t at Kb + t*4096

  stage8k(Kb, &kbuf[0][0][0], tid);
  __syncthreads();                       // drains vmcnt -> tile 0 ready
  float pm[2] = {-1e30f, -1e30f}, zs[2] = {0.f, 0.f};
  int buf = 0;
  for (int t = 0; t < 32; ++t) {
    if (t < 31) stage8k(Kb + (size_t)(t + 1) * 4096, &kbuf[buf ^ 1][0][0], tid);
    const unsigned short* Kt = &kbuf[buf][0][0];
    f32x4 s4[2][4];
#pragma unroll
    for (int jc = 0; jc < 4; ++jc) {
      v8bf k0 = lds_frag(Kt, jc * 16 + lr, g);
      v8bf k1 = lds_frag(Kt, jc * 16 + lr, g + 4);
#pragma unroll
      for (int qg = 0; qg < 2; ++qg) {
        f32x4 z = {0.f, 0.f, 0.f, 0.f};
        z = __builtin_amdgcn_mfma_f32_16x16x32_bf16(k0, aq0[qg], z, 0, 0, 0);
        z = __builtin_amdgcn_mfma_f32_16x16x32_bf16(k1, aq1[qg], z, 0, 0, 0);
        s4[qg][jc] = z;
      }
    }
#pragma unroll
    for (int qg = 0; qg < 2; ++qg) {
      float tv[16];
#pragma unroll
      for (int jc = 0; jc < 4; ++jc)
#pragma unroll
        for (int r = 0; r < 4; ++r) tv[jc * 4 + r] = s4[qg][jc][r] * sscale2;
      float tm = tv[0];
#pragma unroll
      for (int i = 1; i < 16; ++i) tm = fmaxf(tm, tv[i]);
      float nm = fmaxf(pm[qg], tm);
      float acc = zs[qg] * __builtin_amdgcn_exp2f(pm[qg] - nm);
#pragma unroll
      for (int i = 0; i < 16; ++i) acc += __builtin_amdgcn_exp2f(tv[i] - nm);
      zs[qg] = acc; pm[qg] = nm;
    }
    __syncthreads();                     // next tile staged + kbuf[buf] free
    buf ^= 1;
  }
  float wm_l = 0.f;
#pragma unroll
  for (int qg = 0; qg < 2; ++qg) {
    float m = pm[qg], z = zs[qg];
    // merge the 4 groups (lanes lr, lr+16, lr+32, lr+48)
#pragma unroll
    for (int o = 16; o < 64; o <<= 1) {
      float mo = __shfl_xor(m, o);
      float zo = __shfl_xor(z, o);
      float nm = fmaxf(m, mo);
      z = z * __builtin_amdgcn_exp2f(m - nm) + zo * __builtin_amdgcn_exp2f(mo - nm);
      m = nm;
    }
    float iz = 1.0f / z;
    if (g == 0) {
      marr[bh * cS + r0 + qg * 16 + lr] = m;    // log2-domain row max
      izarr[bh * cS + r0 + qg * 16 + lr] = iz;
    }
    wm_l = fmaxf(wm_l, iz);
  }
  float wmax = wave_max(wm_l);
  if (lane == 0) atomicMax(maxiz_slot, __float_as_uint(wmax));
}

// ---------------- attention pass 2: P=u8-quant(softmax) ; ctx += P*V ----------------
// K and V^T tiles staged cooperatively (async global_load_lds, dbuf, 2-phase).
// 32 q-rows/wave (2 q-groups): K/V frags read once per subtile and reused by both
// groups -> staging + barrier + LDS-read cost per unit work halves vs R8.
// plds wave-private per group; same-wave DS ordering covers write->read.
__global__ __launch_bounds__(256) void attn_pass2_kernel(
    const unsigned short* __restrict__ qs, const unsigned short* __restrict__ ks,
    const unsigned short* __restrict__ vT, const float* __restrict__ marr,
    const float* __restrict__ izarr, float* __restrict__ ctx, const float* st,
    unsigned* amax_slot) {
  __shared__ __align__(16) unsigned short kbuf[2][64][64];
  __shared__ __align__(16) unsigned short vbuf[2][64][64];
  __shared__ __align__(16) unsigned short plds[4][2][16][88];
  int tid = threadIdx.x;
  int bh = blockIdx.y, b = bh >> 3, h = bh & 7;
  int wid = tid >> 6, lane = tid & 63;
  int lr = lane & 15, g = lane >> 4, lk = g * 8;
  int r0 = blockIdx.x * 128 + wid * 32;
  float sscale2 = st[26], isa = st[21], cscale = st[22];
  v8bf aq0[2], aq1[2];
  float m2[2], fac[2];
#pragma unroll
  for (int qg = 0; qg < 2; ++qg) {
    const unsigned short* qp = qs + ((size_t)bh * cS + r0 + qg * 16 + lr) * cD + lk;
    aq0[qg] = *(const v8bf*)qp; aq1[qg] = *(const v8bf*)(qp + 32);
    m2[qg] = marr[bh * cS + r0 + qg * 16 + lr];
    fac[qg] = izarr[bh * cS + r0 + qg * 16 + lr] * isa;
  }
  const unsigned short* Kb = ks + (size_t)bh * cS * cD;      // K tile t at +t*4096
  const unsigned short* Vb = vT + (size_t)bh * 32 * 4096;    // V^T tile t at +t*4096
  f32x4 cacc[2][4] = {};

  stage8k(Kb, &kbuf[0][0][0], tid);
  stage8k(Vb, &vbuf[0][0][0], tid);
  __syncthreads();
  int buf = 0;
  for (int t = 0; t < 32; ++t) {
    if (t < 31) {
      stage8k(Kb + (size_t)(t + 1) * 4096, &kbuf[buf ^ 1][0][0], tid);
      stage8k(Vb + (size_t)(t + 1) * 4096, &vbuf[buf ^ 1][0][0], tid);
    }
    const unsigned short* Kt = &kbuf[buf][0][0];
    const unsigned short* Vt = &vbuf[buf][0][0];
    // QK + softmax + packed P store (K frag read once, both q-groups)
#pragma unroll
    for (int jc = 0; jc < 4; ++jc) {
      v8bf k0 = lds_frag(Kt, jc * 16 + lr, g);
      v8bf k1 = lds_frag(Kt, jc * 16 + lr, g + 4);
#pragma unroll
      for (int qg = 0; qg < 2; ++qg) {
        f32x4 z = {0.f, 0.f, 0.f, 0.f};
        z = __builtin_amdgcn_mfma_f32_16x16x32_bf16(k0, aq0[qg], z, 0, 0, 0);
        z = __builtin_amdgcn_mfma_f32_16x16x32_bf16(k1, aq1[qg], z, 0, 0, 0);
        float a0 = fminf(rintf(__builtin_amdgcn_exp2f(__builtin_fmaf(z[0], sscale2, -m2[qg])) * fac[qg]), 255.f);
        float a1 = fminf(rintf(__builtin_amdgcn_exp2f(__builtin_fmaf(z[1], sscale2, -m2[qg])) * fac[qg]), 255.f);
        float a2 = fminf(rintf(__builtin_amdgcn_exp2f(__builtin_fmaf(z[2], sscale2, -m2[qg])) * fac[qg]), 255.f);
        float a3 = fminf(rintf(__builtin_amdgcn_exp2f(__builtin_fmaf(z[3], sscale2, -m2[qg])) * fac[qg]), 255.f);
        uint2 pw;
        pw.x = (__float_as_uint(a0) >> 16) | (__float_as_uint(a1) & 0xFFFF0000u);
        pw.y = (__float_as_uint(a2) >> 16) | (__float_as_uint(a3) & 0xFFFF0000u);
        *(uint2*)&plds[wid][qg][lr][jc * 16 + g * 4] = pw;   // 4 consecutive k as one b64
      }
    }
    // PV: P frags per group, V frag read once and reused by both groups
    v8bf ap0[2], ap1[2];
#pragma unroll
    for (int qg = 0; qg < 2; ++qg) {
      ap0[qg] = *(const v8bf*)&plds[wid][qg][lr][lk];
      ap1[qg] = *(const v8bf*)&plds[wid][qg][lr][32 + lk];
    }
#pragma unroll
    for (int dt = 0; dt < 4; ++dt) {
      v8bf v0 = lds_frag(Vt, dt * 16 + lr, g);
      v8bf v1 = lds_frag(Vt, dt * 16 + lr, g + 4);
#pragma unroll
      for (int qg = 0; qg < 2; ++qg) {
        cacc[qg][dt] = __builtin_amdgcn_mfma_f32_16x16x32_bf16(ap0[qg], v0, cacc[qg][dt], 0, 0, 0);
        cacc[qg][dt] = __builtin_amdgcn_mfma_f32_16x16x32_bf16(ap1[qg], v1, cacc[qg][dt], 0, 0, 0);
      }
    }
    __syncthreads();                     // next tiles staged + bufs free
    buf ^= 1;
  }
  float lmax = 0.f;
#pragma unroll
  for (int qg = 0; qg < 2; ++qg)
#pragma unroll
    for (int dt = 0; dt < 4; ++dt)
#pragma unroll
      for (int r = 0; r < 4; ++r) {
        int qrow = r0 + qg * 16 + g * 4 + r;
        int d = dt * 16 + lr;
        float val = cscale * cacc[qg][dt][r];
        lmax = fmaxf(lmax, fabsf(val));
        ctx[((size_t)qrow * cB + b) * cE + h * cD + d] = val;  // [S][B][E]
      }
  lmax = wave_max(lmax);
  if (lane == 0) atomicMax(amax_slot, __float_as_uint(lmax));
}

// ---------------- launcher ----------------
extern "C" void kernel_launch(void* const* d_in, const int* in_sizes, int n_in, void* d_out,
                              int out_size, void* d_ws, size_t ws_size, hipStream_t stream) {
  (void)in_sizes; (void)n_in; (void)out_size; (void)ws_size;
  const float* x  = (const float*)d_in[0];
  const float* Wq = (const float*)d_in[1];
  const float* Wk = (const float*)d_in[2];
  const float* Wv = (const float*)d_in[3];
  const float* bq = (const float*)d_in[4];
  const float* bk = (const float*)d_in[5];
  const float* bv = (const float*)d_in[6];
  const float* Wo = (const float*)d_in[7];
  const float* bo = (const float*)d_in[8];
  float* out = (float*)d_out;

  char* ws = (char*)d_ws;
  size_t off = 0;
  auto alloc = [&](size_t bytes) { size_t o = off; off += (bytes + 255) & ~(size_t)255; return o; };
  float* st = (float*)(ws + alloc(64 * 4));
  unsigned short* xq  = (unsigned short*)(ws + alloc((size_t)cN * 2));
  unsigned short* wbq = (unsigned short*)(ws + alloc((size_t)cE * cE * 2));  // wbq..wbo contiguous
  unsigned short* wbk = (unsigned short*)(ws + alloc((size_t)cE * cE * 2));
  unsigned short* wbv = (unsigned short*)(ws + alloc((size_t)cE * cE * 2));
  unsigned short* wbo = (unsigned short*)(ws + alloc((size_t)cE * cE * 2));
  float* bfq = (float*)(ws + alloc(cE * 4));   // bfq..bfv contiguous
  float* bfk = (float*)(ws + alloc(cE * 4));
  float* bfv = (float*)(ws + alloc(cE * 4));
  float* bfo = (float*)(ws + alloc(cE * 4));
  float* qf = (float*)(ws + alloc((size_t)cN * 4));   // [BH][S][D]; qf,kf contiguous
  float* kf = (float*)(ws + alloc((size_t)cN * 4));
  float* vf = (float*)(ws + alloc((size_t)cN * 4));
  unsigned short* qsb = (unsigned short*)(ws + alloc((size_t)cN * 2));  // qsb,ksb contiguous
  unsigned short* ksb = (unsigned short*)(ws + alloc((size_t)cN * 2));
  unsigned short* vTb = (unsigned short*)(ws + alloc((size_t)cN * 2));
  float* marr  = (float*)(ws + alloc((size_t)cBH * cS * 4));
  float* izarr = (float*)(ws + alloc((size_t)cBH * cS * 4));
  float* ctxf = qf;                      // alias: qf dead after quant(q)
  unsigned short* cib = (unsigned short*)kf;  // alias: kf dead after quant(k)
  // total ws ~ 87 MB

  int n4 = cN / 4;
  int nw4 = cE * cE / 4;
  hipMemsetAsync(st, 0, 256, stream);
  absmax_kernel<<<1024, 256, 0, stream>>>(x, n4, (unsigned*)(st + 0));
  absmax4_kernel<<<dim3(64, 4), 256, 0, stream>>>(Wq, Wk, Wv, Wo, nw4, (unsigned*)(st + 1));
  scales_kernel<<<1, 1, 0, stream>>>(st, 0);
  quant_x_kernel<<<1024, 256, 0, stream>>>(x, xq, st, n4);
  quant_w4_kernel<<<dim3(64, 4), 256, 0, stream>>>(Wq, Wk, Wv, Wo, wbq, nw4, st);
  bias3_kernel<<<dim3(2, 3), 256, 0, stream>>>(bq, bk, bv, bfq, st);
  gemm_kernel<0><<<dim3(cSB / 64, cE / 64), 256, 0, stream>>>(xq, wbq, bfq, qf, st, 12, 13, (unsigned*)(st + 5));
  gemm_kernel<0><<<dim3(cSB / 64, cE / 64), 256, 0, stream>>>(xq, wbk, bfk, kf, st, 12, 14, (unsigned*)(st + 6));
  gemm_kernel<0><<<dim3(cSB / 64, cE / 64), 256, 0, stream>>>(xq, wbv, bfv, vf, st, 12, 15, (unsigned*)(st + 7));
  scales_kernel<<<1, 1, 0, stream>>>(st, 1);
  quant_qk_kernel<<<dim3(512, 2), 256, 0, stream>>>(qf, qsb, n4, st);
  quant_vT_kernel<<<dim3(cS / 64, cBH), 256, 0, stream>>>(vf, vTb, st);
  attn_pass1_kernel<<<dim3(cS / 128, cBH), 256, 0, stream>>>(qsb, ksb, marr, izarr, st, (unsigned*)(st + 8));
  scales_kernel<<<1, 1, 0, stream>>>(st, 2);
  attn_pass2_kernel<<<dim3(cS / 128, cBH), 256, 0, stream>>>(qsb, ksb, vTb, marr, izarr, ctxf, st, (unsigned*)(st + 9));
  scales_kernel<<<1, 1, 0, stream>>>(st, 3);
  quant_s8_kernel<<<1024, 256, 0, stream>>>(ctxf, cib, n4, st, 23, 1.0f);
  bias_kernel<<<2, 256, 0, stream>>>(bo, bfo, st, 23, 16);
  gemm_kernel<1><<<dim3(cSB / 64, cE / 64), 256, 0, stream>>>(cib, wbo, bfo, out, st, 23, 16, (unsigned*)(st + 10));
  scales_kernel<<<1, 1, 0, stream>>>(st, 4);
  final_quant_kernel<<<1024, 256, 0, stream>>>(out, st, n4);
}

// Round 11
// 485.515 us; speedup vs baseline: 1.5975x; 1.1018x over previous
//
#include <hip/hip_runtime.h>

// QuantMHSANet: Brevitas-style per-tensor fake-quant MHSA.
// S=2048 B=4 E=512 H=8 D=64. All GEMMs run as integer-exact bf16 MFMA.
constexpr int cS = 2048, cB = 4, cE = 512, cH = 8, cD = 64;
constexpr int cSB = cS * cB;   // 8192 rows
constexpr int cBH = cB * cH;   // 32 (b,h) pairs
constexpr int cN  = cSB * cE;  // 4194304 elements

typedef __bf16 v8bf  __attribute__((ext_vector_type(8)));
typedef float  f32x4 __attribute__((ext_vector_type(4)));

constexpr float cLOG2E = 1.4426950408889634f;

// ---- stat slots (float, raw amax values; scales computed inline by consumers) ----
// 0 amax_x | 1..4 amax_w(q,k,v,o) | 5 amax_q 6 amax_k 7 amax_v | 8 max_invz
// 9 amax_ctx | 10 amax_y

// Quantized ints |v|<=255 have <=8 significand bits -> bf16 truncation is exact.
__device__ __forceinline__ unsigned short q2bf(float f) {
  return (unsigned short)(__float_as_uint(f) >> 16);
}
__device__ __forceinline__ float clip8(float t) { return fminf(fmaxf(t, -128.f), 127.f); }
__device__ __forceinline__ float sc127(float amax) { return fmaxf(amax, 1e-8f) / 127.f; }
__device__ __forceinline__ float wave_max(float v) {
#pragma unroll
  for (int o = 32; o > 0; o >>= 1) v = fmaxf(v, __shfl_down(v, o));
  return v;
}

// ---- cooperative async staging of one 64x64 bf16 tile ----
// global_load_lds: LDS dest = wave-uniform base + lane*16 (linear). The XOR chunk
// swizzle (chunk ^= row&7, 16B chunks, 8 chunks/row) is applied on the GLOBAL source
// address (rule #21: linear dest + inverse-swz source + swz on read). Involution.
// Contiguous variant (8KB block):
__device__ __forceinline__ void stage8k(const unsigned short* __restrict__ gsrc,
                                        unsigned short* lds, int tid) {
  int w = tid >> 6;
#pragma unroll
  for (int is = 0; is < 2; ++is) {
    int c = is * 256 + tid;                              // dest chunk 0..511
    int cp = (c & ~7) | ((c & 7) ^ ((c >> 3) & 7));      // src chunk (self-inverse)
    const char* g = (const char*)gsrc + (size_t)cp * 16;
    char* l = (char*)lds + (size_t)(is * 4096 + w * 1024);  // wave-uniform base
    __builtin_amdgcn_global_load_lds(
        (const __attribute__((address_space(1))) unsigned int*)g,
        (__attribute__((address_space(3))) unsigned int*)l, 16, 0, 0);
  }
}
// Strided variant: 64 rows x 64 cols from a row-major [row][cE] source.
__device__ __forceinline__ void stage_rows(const unsigned short* __restrict__ g0,
                                           unsigned short* lds, int tid) {
  int w = tid >> 6;
#pragma unroll
  for (int is = 0; is < 2; ++is) {
    int c = is * 256 + tid;                              // dest chunk 0..511
    int row = c >> 3;
    int kc = (c & 7) ^ (row & 7);                        // swizzled source chunk
    const char* g = (const char*)(g0 + (size_t)row * cE + kc * 8);
    char* l = (char*)lds + (size_t)(is * 4096 + w * 1024);
    __builtin_amdgcn_global_load_lds(
        (const __attribute__((address_space(1))) unsigned int*)g,
        (__attribute__((address_space(3))) unsigned int*)l, 16, 0, 0);
  }
}
// swizzled b128 fragment read from a staged [64][64] bf16 tile
__device__ __forceinline__ v8bf lds_frag(const unsigned short* tile, int row, int chunk) {
  int sc = chunk ^ (row & 7);
  return *(const v8bf*)((const char*)tile + row * 128 + sc * 16);
}

// ---------------- reductions ----------------
__global__ void absmax_kernel(const float* __restrict__ p, int n4, unsigned* slot) {
  int tid = blockIdx.x * blockDim.x + threadIdx.x, stride = gridDim.x * blockDim.x;
  float m = 0.f;
  for (int i = tid; i < n4; i += stride) {
    float4 v = ((const float4*)p)[i];
    m = fmaxf(m, fmaxf(fmaxf(fabsf(v.x), fabsf(v.y)), fmaxf(fabsf(v.z), fabsf(v.w))));
  }
  m = wave_max(m);
  __shared__ float sm[4];
  int lane = threadIdx.x & 63, wid = threadIdx.x >> 6;
  if (lane == 0) sm[wid] = m;
  __syncthreads();
  if (threadIdx.x == 0) {
    float mm = sm[0];
    for (int w = 1; w < (int)blockDim.x / 64; ++w) mm = fmaxf(mm, sm[w]);
    atomicMax(slot, __float_as_uint(mm));
  }
}

// 4 weight matrices in one launch (blockIdx.y selects)
__global__ void absmax4_kernel(const float* __restrict__ w0, const float* __restrict__ w1,
                               const float* __restrict__ w2, const float* __restrict__ w3,
                               int n4, unsigned* slots) {
  int y = blockIdx.y;
  const float* p = (y == 0) ? w0 : (y == 1) ? w1 : (y == 2) ? w2 : w3;
  int tid = blockIdx.x * blockDim.x + threadIdx.x, stride = gridDim.x * blockDim.x;
  float m = 0.f;
  for (int i = tid; i < n4; i += stride) {
    float4 v = ((const float4*)p)[i];
    m = fmaxf(m, fmaxf(fmaxf(fabsf(v.x), fabsf(v.y)), fmaxf(fabsf(v.z), fabsf(v.w))));
  }
  m = wave_max(m);
  __shared__ float sm[4];
  int lane = threadIdx.x & 63, wid = threadIdx.x >> 6;
  if (lane == 0) sm[wid] = m;
  __syncthreads();
  if (threadIdx.x == 0) {
    float mm = fmaxf(fmaxf(sm[0], sm[1]), fmaxf(sm[2], sm[3]));
    atomicMax(slots + y, __float_as_uint(mm));
  }
}

// ---------------- elementwise quantizers (scales computed inline) ----------------
__global__ void quant_x_kernel(const float* __restrict__ x, unsigned short* __restrict__ xq,
                               const float* st, int n4) {
  float s0 = sc127(st[0]);
  float si = fmaxf(s0 * 127.f, 1e-8f) / 127.f;   // identical formula to old stage-0
  int tid = blockIdx.x * blockDim.x + threadIdx.x, stride = gridDim.x * blockDim.x;
  for (int i = tid; i < n4; i += stride) {
    float4 v = ((const float4*)x)[i];
    ushort4 o; float t;
    t = s0 * clip8(rintf(v.x / s0)); o.x = q2bf(clip8(rintf(t / si)));
    t = s0 * clip8(rintf(v.y / s0)); o.y = q2bf(clip8(rintf(t / si)));
    t = s0 * clip8(rintf(v.z / s0)); o.z = q2bf(clip8(rintf(t / si)));
    t = s0 * clip8(rintf(v.w / s0)); o.w = q2bf(clip8(rintf(t / si)));
    ((ushort4*)xq)[i] = o;
  }
}

// 4 weight matrices quantized in one launch; outputs contiguous at outbase + y*cE*cE
__global__ void quant_w4_kernel(const float* __restrict__ w0, const float* __restrict__ w1,
                                const float* __restrict__ w2, const float* __restrict__ w3,
                                unsigned short* __restrict__ outbase, int n4, const float* st) {
  int y = blockIdx.y;
  const float* in = (y == 0) ? w0 : (y == 1) ? w1 : (y == 2) ? w2 : w3;
  unsigned short* outp = outbase + (size_t)y * cE * cE;
  float s = sc127(st[1 + y]);
  int tid = blockIdx.x * blockDim.x + threadIdx.x, stride = gridDim.x * blockDim.x;
  for (int i = tid; i < n4; i += stride) {
    float4 v = ((const float4*)in)[i];
    ushort4 o;
    o.x = q2bf(clip8(rintf(v.x / s)));
    o.y = q2bf(clip8(rintf(v.y / s)));
    o.z = q2bf(clip8(rintf(v.z / s)));
    o.w = q2bf(clip8(rintf(v.w / s)));
    ((ushort4*)outp)[i] = o;
  }
}

// ctx quantizer (scale from raw amax slot)
__global__ void quant_ctx_kernel(const float* __restrict__ in, unsigned short* __restrict__ outp,
                                 int n4, const float* st) {
  float s = sc127(st[9]);
  int tid = blockIdx.x * blockDim.x + threadIdx.x, stride = gridDim.x * blockDim.x;
  for (int i = tid; i < n4; i += stride) {
    float4 v = ((const float4*)in)[i];
    ushort4 o;
    o.x = q2bf(clip8(rintf(v.x / s)));
    o.y = q2bf(clip8(rintf(v.y / s)));
    o.z = q2bf(clip8(rintf(v.z / s)));
    o.w = q2bf(clip8(rintf(v.w / s)));
    ((ushort4*)outp)[i] = o;
  }
}

// q and k quantized in one launch (blockIdx.y: 0=q premul 1/8, 1=k)
__global__ void quant_qk_kernel(const float* __restrict__ qf, unsigned short* __restrict__ qsb,
                                int n4, const float* st) {
  int y = blockIdx.y;
  const float* in = qf + (size_t)y * cN;
  unsigned short* outp = qsb + (size_t)y * cN;
  float s = y ? sc127(st[6]) : (fmaxf(st[5] * 0.125f, 1e-8f) / 127.f);
  float premul = y ? 1.0f : 0.125f;
  int tid = blockIdx.x * blockDim.x + threadIdx.x, stride = gridDim.x * blockDim.x;
  for (int i = tid; i < n4; i += stride) {
    float4 v = ((const float4*)in)[i];
    ushort4 o;
    o.x = q2bf(clip8(rintf(v.x * premul / s)));
    o.y = q2bf(clip8(rintf(v.y * premul / s)));
    o.z = q2bf(clip8(rintf(v.z * premul / s)));
    o.w = q2bf(clip8(rintf(v.w * premul / s)));
    ((ushort4*)outp)[i] = o;
  }
}

// q/k/v biases in one launch; outputs contiguous at bdst + y*512
__global__ void bias3_kernel(const float* __restrict__ b0, const float* __restrict__ b1,
                             const float* __restrict__ b2, float* __restrict__ bdst,
                             const float* st) {
  int y = blockIdx.y;
  const float* bsrc = (y == 0) ? b0 : (y == 1) ? b1 : b2;
  int f = blockIdx.x * blockDim.x + threadIdx.x;
  if (f < cE) {
    float s0 = sc127(st[0]);
    float si = fmaxf(s0 * 127.f, 1e-8f) / 127.f;
    float s = si * sc127(st[1 + y]);
    bdst[y * cE + f] = s * rintf(bsrc[f] / s);
  }
}

// out-proj bias (scale = s_c * s_wo from raw slots 9, 4)
__global__ void bias_o_kernel(const float* __restrict__ bsrc, float* __restrict__ bdst,
                              const float* st) {
  int f = blockIdx.x * blockDim.x + threadIdx.x;
  if (f < cE) {
    float s = sc127(st[9]) * sc127(st[4]);
    bdst[f] = s * rintf(bsrc[f] / s);   // int32 clip is a no-op at these magnitudes
  }
}

// V: [BH][S][D] f32 -> quantized, TILED transposed layout [bh][kt/64][d=64][s%64] bf16
// so each (bh, kt) V^T tile is one contiguous 8KB block for global_load_lds staging.
__global__ __launch_bounds__(256) void quant_vT_kernel(const float* __restrict__ v,
                                                       unsigned short* __restrict__ vT,
                                                       const float* st) {
  __shared__ unsigned short tile[64][65];
  int bh = blockIdx.y, bx = blockIdx.x, s0 = bx * 64;
  float sv = sc127(st[7]);
  int td = threadIdx.x & 63, tr = threadIdx.x >> 6;
  for (int r = tr; r < 64; r += 4)
    tile[r][td] = q2bf(clip8(rintf(v[((size_t)bh * cS + s0 + r) * cD + td] / sv)));
  __syncthreads();
  for (int r = tr; r < 64; r += 4)
    vT[((size_t)(bh * 32 + bx) * 64 + r) * 64 + td] = tile[td][r];
}

__global__ void final_quant_kernel(float* __restrict__ y, const float* st, int n4) {
  float s = sc127(st[10]);
  int tid = blockIdx.x * blockDim.x + threadIdx.x, stride = gridDim.x * blockDim.x;
  for (int i = tid; i < n4; i += stride) {
    float4 v = ((float4*)y)[i];
    v.x = s * clip8(rintf(v.x / s)); v.y = s * clip8(rintf(v.y / s));
    v.z = s * clip8(rintf(v.z / s)); v.w = s * clip8(rintf(v.w / s));
    ((float4*)y)[i] = v;
  }
}

// ---------------- integer-exact bf16 MFMA GEMM with LDS staging ----------------
// C[row,col] = sum_e A[row][e]*W[col][e]; both K-major (512 cols bf16-int).
// A and B 64x64 k-chunks cooperatively staged (async global_load_lds, dbuf, 2-phase)
// -> removes R7-style per-fragment latency exposure + 2x intra-block read redundancy.
// MODE 0: fused q/k/v projection, blockIdx.y=(wsel*8+colblk), output [B][H][S][D] at
//         outbase + wsel*cN, amax -> slots[wsel]. MODE 1: out-proj, row-major [SB][E].
template <int MODE>
__global__ __launch_bounds__(256) void gemm_kernel(const unsigned short* __restrict__ A,
                                                   const unsigned short* __restrict__ Wbase,
                                                   const float* __restrict__ biasbase,
                                                   float* __restrict__ outbase, const float* st,
                                                   unsigned* amax_base) {
  __shared__ __align__(16) unsigned short abuf[2][64][64];
  __shared__ __align__(16) unsigned short bbuf[2][64][64];
  int tid = threadIdx.x, wid = tid >> 6, lane = tid & 63;
  int wm = wid >> 1, wn = wid & 1;
  int lr = lane & 15, g = lane >> 4;
  int row0 = blockIdx.x * 64;
  int wsel = (MODE == 0) ? (blockIdx.y >> 3) : 0;
  int col0 = (MODE == 0) ? ((blockIdx.y & 7) * 64) : (blockIdx.y * 64);

  float scale;
  float* out;
  const float* bias;
  unsigned* amax_slot;
  if (MODE == 0) {
    float s0 = sc127(st[0]);
    float si = fmaxf(s0 * 127.f, 1e-8f) / 127.f;
    scale = si * sc127(st[1 + wsel]);
    out = outbase + (size_t)wsel * cN;
    bias = biasbase + wsel * cE;
    amax_slot = amax_base + wsel;
  } else {
    scale = sc127(st[9]) * sc127(st[4]);
    out = outbase;
    bias = biasbase;
    amax_slot = amax_base;
  }
  const unsigned short* Ab = A + (size_t)row0 * cE;
  const unsigned short* Bb = Wbase + (size_t)wsel * cE * cE + (size_t)col0 * cE;

  stage_rows(Ab, &abuf[0][0][0], tid);
  stage_rows(Bb, &bbuf[0][0][0], tid);
  __syncthreads();
  f32x4 acc[2][2] = {};
  int buf = 0;
  for (int kt = 0; kt < 8; ++kt) {
    if (kt < 7) {
      stage_rows(Ab + (kt + 1) * 64, &abuf[buf ^ 1][0][0], tid);
      stage_rows(Bb + (kt + 1) * 64, &bbuf[buf ^ 1][0][0], tid);
    }
    const unsigned short* At = &abuf[buf][0][0];
    const unsigned short* Bt = &bbuf[buf][0][0];
#pragma unroll
    for (int e = 0; e < 2; ++e) {   // two k32 substeps within the k64 chunk
      v8bf a0 = lds_frag(At, wm * 32 + lr, e * 4 + g);
      v8bf a1 = lds_frag(At, wm * 32 + 16 + lr, e * 4 + g);
      v8bf b0 = lds_frag(Bt, wn * 32 + lr, e * 4 + g);
      v8bf b1 = lds_frag(Bt, wn * 32 + 16 + lr, e * 4 + g);
      acc[0][0] = __builtin_amdgcn_mfma_f32_16x16x32_bf16(a0, b0, acc[0][0], 0, 0, 0);
      acc[0][1] = __builtin_amdgcn_mfma_f32_16x16x32_bf16(a0, b1, acc[0][1], 0, 0, 0);
      acc[1][0] = __builtin_amdgcn_mfma_f32_16x16x32_bf16(a1, b0, acc[1][0], 0, 0, 0);
      acc[1][1] = __builtin_amdgcn_mfma_f32_16x16x32_bf16(a1, b1, acc[1][1], 0, 0, 0);
    }
    __syncthreads();
    buf ^= 1;
  }
  float lmax = 0.f;
#pragma unroll
  for (int mi = 0; mi < 2; ++mi)
#pragma unroll
    for (int ni = 0; ni < 2; ++ni)
#pragma unroll
      for (int r = 0; r < 4; ++r) {
        int row = row0 + wm * 32 + mi * 16 + g * 4 + r;   // C/D: row=(l>>4)*4+reg
        int col = col0 + wn * 32 + ni * 16 + lr;          //      col=l&15
        float val = scale * acc[mi][ni][r] + bias[col];
        lmax = fmaxf(lmax, fabsf(val));
        if (MODE == 0) {
          int s = row >> 2, bb = row & 3, h = col >> 6, d = col & 63;
          out[(((size_t)(bb * cH + h)) * cS + s) * cD + d] = val;
        } else {
          out[(size_t)row * cE + col] = val;
        }
      }
  lmax = wave_max(lmax);
  if (lane == 0) atomicMax(amax_slot, __float_as_uint(lmax));
}

// ---------------- attention pass 1: per-row (m2, 1/Z) in log2 domain ----------------
// Swapped QK (A=K frag, B=Q frag); 32 q-rows per wave (2 q-groups of 16) so each
// staged K tile is amortized over 2x MFMA work; K frag read once per jc, used by
// both groups. K tiles staged via async global_load_lds, dbuf, 2-phase.
__global__ __launch_bounds__(256) void attn_pass1_kernel(const unsigned short* __restrict__ qs,
                                                         const unsigned short* __restrict__ ks,
                                                         float* __restrict__ marr,
                                                         float* __restrict__ izarr,
                                                         const float* st, unsigned* maxiz_slot) {
  __shared__ __align__(16) unsigned short kbuf[2][64][64];
  int tid = threadIdx.x;
  int bh = blockIdx.y;
  int wid = tid >> 6, lane = tid & 63;
  int lr = lane & 15, g = lane >> 4, lk = g * 8;
  int r0 = blockIdx.x * 128 + wid * 32;
  float sq = fmaxf(st[5] * 0.125f, 1e-8f) / 127.f;
  float sk = sc127(st[6]);
  float sscale2 = (sq * sk) * cLOG2E;   // s_q*s_k*log2e (log2-domain scores)
  v8bf aq0[2], aq1[2];
#pragma unroll
  for (int qg = 0; qg < 2; ++qg) {
    const unsigned short* qp = qs + ((size_t)bh * cS + r0 + qg * 16 + lr) * cD + lk;
    aq0[qg] = *(const v8bf*)qp; aq1[qg] = *(const v8bf*)(qp + 32);
  }
  const unsigned short* Kb = ks + (size_t)bh * cS * cD;   // 64-row tile t at Kb + t*4096

  stage8k(Kb, &kbuf[0][0][0], tid);
  __syncthreads();                       // drains vmcnt -> tile 0 ready
  float pm[2] = {-1e30f, -1e30f}, zs[2] = {0.f, 0.f};
  int buf = 0;
  for (int t = 0; t < 32; ++t) {
    if (t < 31) stage8k(Kb + (size_t)(t + 1) * 4096, &kbuf[buf ^ 1][0][0], tid);
    const unsigned short* Kt = &kbuf[buf][0][0];
    f32x4 s4[2][4];
#pragma unroll
    for (int jc = 0; jc < 4; ++jc) {
      v8bf k0 = lds_frag(Kt, jc * 16 + lr, g);
      v8bf k1 = lds_frag(Kt, jc * 16 + lr, g + 4);
#pragma unroll
      for (int qg = 0; qg < 2; ++qg) {
        f32x4 z = {0.f, 0.f, 0.f, 0.f};
        z = __builtin_amdgcn_mfma_f32_16x16x32_bf16(k0, aq0[qg], z, 0, 0, 0);
        z = __builtin_amdgcn_mfma_f32_16x16x32_bf16(k1, aq1[qg], z, 0, 0, 0);
        s4[qg][jc] = z;
      }
    }
#pragma unroll
    for (int qg = 0; qg < 2; ++qg) {
      float tv[16];
#pragma unroll
      for (int jc = 0; jc < 4; ++jc)
#pragma unroll
        for (int r = 0; r < 4; ++r) tv[jc * 4 + r] = s4[qg][jc][r] * sscale2;
      float tm = tv[0];
#pragma unroll
      for (int i = 1; i < 16; ++i) tm = fmaxf(tm, tv[i]);
      float nm = fmaxf(pm[qg], tm);
      float acc = zs[qg] * __builtin_amdgcn_exp2f(pm[qg] - nm);
#pragma unroll
      for (int i = 0; i < 16; ++i) acc += __builtin_amdgcn_exp2f(tv[i] - nm);
      zs[qg] = acc; pm[qg] = nm;
    }
    __syncthreads();                     // next tile staged + kbuf[buf] free
    buf ^= 1;
  }
  float wm_l = 0.f;
#pragma unroll
  for (int qg = 0; qg < 2; ++qg) {
    float m = pm[qg], z = zs[qg];
    // merge the 4 groups (lanes lr, lr+16, lr+32, lr+48)
#pragma unroll
    for (int o = 16; o < 64; o <<= 1) {
      float mo = __shfl_xor(m, o);
      float zo = __shfl_xor(z, o);
      float nm = fmaxf(m, mo);
      z = z * __builtin_amdgcn_exp2f(m - nm) + zo * __builtin_amdgcn_exp2f(mo - nm);
      m = nm;
    }
    float iz = 1.0f / z;
    if (g == 0) {
      marr[bh * cS + r0 + qg * 16 + lr] = m;    // log2-domain row max
      izarr[bh * cS + r0 + qg * 16 + lr] = iz;
    }
    wm_l = fmaxf(wm_l, iz);
  }
  float wmax = wave_max(wm_l);
  if (lane == 0) atomicMax(maxiz_slot, __float_as_uint(wmax));
}

// ---------------- attention pass 2: P=u8-quant(softmax) ; ctx += P*V ----------------
// K and V^T tiles staged cooperatively (async global_load_lds, dbuf, 2-phase).
// 32 q-rows/wave (2 q-groups): K/V frags read once per subtile and reused by both
// groups. plds wave-private per group; same-wave DS ordering covers write->read.
__global__ __launch_bounds__(256) void attn_pass2_kernel(
    const unsigned short* __restrict__ qs, const unsigned short* __restrict__ ks,
    const unsigned short* __restrict__ vT, const float* __restrict__ marr,
    const float* __restrict__ izarr, float* __restrict__ ctx, const float* st,
    unsigned* amax_slot) {
  __shared__ __align__(16) unsigned short kbuf[2][64][64];
  __shared__ __align__(16) unsigned short vbuf[2][64][64];
  __shared__ __align__(16) unsigned short plds[4][2][16][88];
  int tid = threadIdx.x;
  int bh = blockIdx.y, b = bh >> 3, h = bh & 7;
  int wid = tid >> 6, lane = tid & 63;
  int lr = lane & 15, g = lane >> 4, lk = g * 8;
  int r0 = blockIdx.x * 128 + wid * 32;
  float sq = fmaxf(st[5] * 0.125f, 1e-8f) / 127.f;
  float sk = sc127(st[6]);
  float sscale2 = (sq * sk) * cLOG2E;
  float sa = fmaxf(st[8], 1e-8f) / 255.f;
  float isa = 1.f / sa;
  float cscale = sa * sc127(st[7]);
  v8bf aq0[2], aq1[2];
  float m2[2], fac[2];
#pragma unroll
  for (int qg = 0; qg < 2; ++qg) {
    const unsigned short* qp = qs + ((size_t)bh * cS + r0 + qg * 16 + lr) * cD + lk;
    aq0[qg] = *(const v8bf*)qp; aq1[qg] = *(const v8bf*)(qp + 32);
    m2[qg] = marr[bh * cS + r0 + qg * 16 + lr];
    fac[qg] = izarr[bh * cS + r0 + qg * 16 + lr] * isa;
  }
  const unsigned short* Kb = ks + (size_t)bh * cS * cD;      // K tile t at +t*4096
  const unsigned short* Vb = vT + (size_t)bh * 32 * 4096;    // V^T tile t at +t*4096
  f32x4 cacc[2][4] = {};

  stage8k(Kb, &kbuf[0][0][0], tid);
  stage8k(Vb, &vbuf[0][0][0], tid);
  __syncthreads();
  int buf = 0;
  for (int t = 0; t < 32; ++t) {
    if (t < 31) {
      stage8k(Kb + (size_t)(t + 1) * 4096, &kbuf[buf ^ 1][0][0], tid);
      stage8k(Vb + (size_t)(t + 1) * 4096, &vbuf[buf ^ 1][0][0], tid);
    }
    const unsigned short* Kt = &kbuf[buf][0][0];
    const unsigned short* Vt = &vbuf[buf][0][0];
    // QK + softmax + packed P store (K frag read once, both q-groups)
#pragma unroll
    for (int jc = 0; jc < 4; ++jc) {
      v8bf k0 = lds_frag(Kt, jc * 16 + lr, g);
      v8bf k1 = lds_frag(Kt, jc * 16 + lr, g + 4);
#pragma unroll
      for (int qg = 0; qg < 2; ++qg) {
        f32x4 z = {0.f, 0.f, 0.f, 0.f};
        z = __builtin_amdgcn_mfma_f32_16x16x32_bf16(k0, aq0[qg], z, 0, 0, 0);
        z = __builtin_amdgcn_mfma_f32_16x16x32_bf16(k1, aq1[qg], z, 0, 0, 0);
        float a0 = fminf(rintf(__builtin_amdgcn_exp2f(__builtin_fmaf(z[0], sscale2, -m2[qg])) * fac[qg]), 255.f);
        float a1 = fminf(rintf(__builtin_amdgcn_exp2f(__builtin_fmaf(z[1], sscale2, -m2[qg])) * fac[qg]), 255.f);
        float a2 = fminf(rintf(__builtin_amdgcn_exp2f(__builtin_fmaf(z[2], sscale2, -m2[qg])) * fac[qg]), 255.f);
        float a3 = fminf(rintf(__builtin_amdgcn_exp2f(__builtin_fmaf(z[3], sscale2, -m2[qg])) * fac[qg]), 255.f);
        uint2 pw;
        pw.x = (__float_as_uint(a0) >> 16) | (__float_as_uint(a1) & 0xFFFF0000u);
        pw.y = (__float_as_uint(a2) >> 16) | (__float_as_uint(a3) & 0xFFFF0000u);
        *(uint2*)&plds[wid][qg][lr][jc * 16 + g * 4] = pw;   // 4 consecutive k as one b64
      }
    }
    // PV: P frags per group, V frag read once and reused by both groups
    v8bf ap0[2], ap1[2];
#pragma unroll
    for (int qg = 0; qg < 2; ++qg) {
      ap0[qg] = *(const v8bf*)&plds[wid][qg][lr][lk];
      ap1[qg] = *(const v8bf*)&plds[wid][qg][lr][32 + lk];
    }
#pragma unroll
    for (int dt = 0; dt < 4; ++dt) {
      v8bf v0 = lds_frag(Vt, dt * 16 + lr, g);
      v8bf v1 = lds_frag(Vt, dt * 16 + lr, g + 4);
#pragma unroll
      for (int qg = 0; qg < 2; ++qg) {
        cacc[qg][dt] = __builtin_amdgcn_mfma_f32_16x16x32_bf16(ap0[qg], v0, cacc[qg][dt], 0, 0, 0);
        cacc[qg][dt] = __builtin_amdgcn_mfma_f32_16x16x32_bf16(ap1[qg], v1, cacc[qg][dt], 0, 0, 0);
      }
    }
    __syncthreads();                     // next tiles staged + bufs free
    buf ^= 1;
  }
  float lmax = 0.f;
#pragma unroll
  for (int qg = 0; qg < 2; ++qg)
#pragma unroll
    for (int dt = 0; dt < 4; ++dt)
#pragma unroll
      for (int r = 0; r < 4; ++r) {
        int qrow = r0 + qg * 16 + g * 4 + r;
        int d = dt * 16 + lr;
        float val = cscale * cacc[qg][dt][r];
        lmax = fmaxf(lmax, fabsf(val));
        ctx[((size_t)qrow * cB + b) * cE + h * cD + d] = val;  // [S][B][E]
      }
  lmax = wave_max(lmax);
  if (lane == 0) atomicMax(amax_slot, __float_as_uint(lmax));
}

// ---------------- launcher ----------------
extern "C" void kernel_launch(void* const* d_in, const int* in_sizes, int n_in, void* d_out,
                              int out_size, void* d_ws, size_t ws_size, hipStream_t stream) {
  (void)in_sizes; (void)n_in; (void)out_size; (void)ws_size;
  const float* x  = (const float*)d_in[0];
  const float* Wq = (const float*)d_in[1];
  const float* Wk = (const float*)d_in[2];
  const float* Wv = (const float*)d_in[3];
  const float* bq = (const float*)d_in[4];
  const float* bk = (const float*)d_in[5];
  const float* bv = (const float*)d_in[6];
  const float* Wo = (const float*)d_in[7];
  const float* bo = (const float*)d_in[8];
  float* out = (float*)d_out;

  char* ws = (char*)d_ws;
  size_t off = 0;
  auto alloc = [&](size_t bytes) { size_t o = off; off += (bytes + 255) & ~(size_t)255; return o; };
  float* st = (float*)(ws + alloc(64 * 4));
  unsigned short* xq  = (unsigned short*)(ws + alloc((size_t)cN * 2));
  unsigned short* wbq = (unsigned short*)(ws + alloc((size_t)cE * cE * 2));  // wbq..wbo contiguous
  unsigned short* wbk = (unsigned short*)(ws + alloc((size_t)cE * cE * 2));
  unsigned short* wbv = (unsigned short*)(ws + alloc((size_t)cE * cE * 2));
  unsigned short* wbo = (unsigned short*)(ws + alloc((size_t)cE * cE * 2));
  float* bfq = (float*)(ws + alloc(cE * 4));   // bfq..bfv contiguous
  float* bfk = (float*)(ws + alloc(cE * 4));
  float* bfv = (float*)(ws + alloc(cE * 4));
  float* bfo = (float*)(ws + alloc(cE * 4));
  float* qf = (float*)(ws + alloc((size_t)cN * 4));   // [BH][S][D]; qf,kf,vf contiguous
  float* kf = (float*)(ws + alloc((size_t)cN * 4));
  float* vf = (float*)(ws + alloc((size_t)cN * 4));
  unsigned short* qsb = (unsigned short*)(ws + alloc((size_t)cN * 2));  // qsb,ksb contiguous
  unsigned short* ksb = (unsigned short*)(ws + alloc((size_t)cN * 2));
  unsigned short* vTb = (unsigned short*)(ws + alloc((size_t)cN * 2));
  float* marr  = (float*)(ws + alloc((size_t)cBH * cS * 4));
  float* izarr = (float*)(ws + alloc((size_t)cBH * cS * 4));
  float* ctxf = qf;                      // alias: qf dead after quant(q)
  unsigned short* cib = (unsigned short*)kf;  // alias: kf dead after quant(k)
  // total ws ~ 87 MB

  int n4 = cN / 4;
  int nw4 = cE * cE / 4;
  (void)kf; (void)vf; (void)bfk; (void)bfv;
  hipMemsetAsync(st, 0, 256, stream);
  absmax_kernel<<<1024, 256, 0, stream>>>(x, n4, (unsigned*)(st + 0));
  absmax4_kernel<<<dim3(64, 4), 256, 0, stream>>>(Wq, Wk, Wv, Wo, nw4, (unsigned*)(st + 1));
  quant_x_kernel<<<1024, 256, 0, stream>>>(x, xq, st, n4);
  quant_w4_kernel<<<dim3(64, 4), 256, 0, stream>>>(Wq, Wk, Wv, Wo, wbq, nw4, st);
  bias3_kernel<<<dim3(2, 3), 256, 0, stream>>>(bq, bk, bv, bfq, st);
  gemm_kernel<0><<<dim3(cSB / 64, 24), 256, 0, stream>>>(xq, wbq, bfq, qf, st, (unsigned*)(st + 5));
  quant_qk_kernel<<<dim3(512, 2), 256, 0, stream>>>(qf, qsb, n4, st);
  quant_vT_kernel<<<dim3(cS / 64, cBH), 256, 0, stream>>>(vf, vTb, st);
  attn_pass1_kernel<<<dim3(cS / 128, cBH), 256, 0, stream>>>(qsb, ksb, marr, izarr, st, (unsigned*)(st + 8));
  attn_pass2_kernel<<<dim3(cS / 128, cBH), 256, 0, stream>>>(qsb, ksb, vTb, marr, izarr, ctxf, st, (unsigned*)(st + 9));
  quant_ctx_kernel<<<1024, 256, 0, stream>>>(ctxf, cib, n4, st);
  bias_o_kernel<<<2, 256, 0, stream>>>(bo, bfo, st);
  gemm_kernel<1><<<dim3(cSB / 64, cE / 64), 256, 0, stream>>>(cib, wbo, bfo, out, st, (unsigned*)(st + 10));
  final_quant_kernel<<<1024, 256, 0, stream>>>(out, st, n4);
}